// Round 1
// baseline (8638.895 us; speedup 1.0000x reference)
//
#include <hip/hip_runtime.h>
#include <hip/hip_bf16.h>
#include <math.h>

#define SEQ 1024
#define EMB 768
#define NHEAD 12
#define HDIM 64
#define NLAYER 4
#define FFDIM 2048
#define BATCH 2
#define ROWS (BATCH * SEQ)   // 2048

// ---------------- embed: h = x + sinusoidal_pe + thought_pe ----------------
__global__ void embed_kernel(const float* __restrict__ x,
                             const float* __restrict__ tpe,
                             float* __restrict__ h,
                             const int* __restrict__ tt_p,
                             const int* __restrict__ rtc_p) {
    int idx = blockIdx.x * blockDim.x + threadIdx.x;  // over B*S*E
    if (idx >= BATCH * SEQ * EMB) return;
    int e = idx % EMB;
    int s = (idx / EMB) % SEQ;
    int nt = *tt_p + 1;
    int rtc = *rtc_p;
    float val;
    if (s < rtc * nt) {
        int p = s / nt;
        int t = s % nt;
        int i2 = e & ~1;
        double div = exp(-(double)i2 * log(10000.0) / (double)EMB);
        double ang = (double)p * div;
        float pe = (e & 1) ? (float)cos(ang) : (float)sin(ang);
        val = x[idx] + pe + tpe[t * EMB + e];
    } else {
        val = 0.0f;
    }
    h[idx] = val;
}

// ---------------- generic tiled GEMM: C = A @ W^T + bias, optional GELU ----
// A: M x K row-major; W: N x K row-major; C: M x N. M,N % 64 == 0, K % 16 == 0.
#define BM 64
#define BN 64
#define BKK 16
__global__ void gemm_bias_act(const float* __restrict__ A,
                              const float* __restrict__ W,
                              const float* __restrict__ bias,
                              float* __restrict__ C,
                              int M, int N, int K, int act) {
    __shared__ float As[BKK][BM + 1];
    __shared__ float Ws[BKK][BN + 1];
    int bm = blockIdx.y * BM;
    int bn = blockIdx.x * BN;
    int tid = threadIdx.x;           // 256 threads
    int tr = tid >> 4;               // 0..15
    int tc = tid & 15;               // 0..15
    float acc[4][4];
#pragma unroll
    for (int i = 0; i < 4; i++)
#pragma unroll
        for (int j = 0; j < 4; j++) acc[i][j] = 0.0f;

    for (int k0 = 0; k0 < K; k0 += BKK) {
#pragma unroll
        for (int i = 0; i < 4; i++) {
            int lin = tid + 256 * i;         // 0..1023
            int m = lin >> 4, kk = lin & 15;
            As[kk][m] = A[(size_t)(bm + m) * K + k0 + kk];
        }
#pragma unroll
        for (int i = 0; i < 4; i++) {
            int lin = tid + 256 * i;
            int n = lin >> 4, kk = lin & 15;
            Ws[kk][n] = W[(size_t)(bn + n) * K + k0 + kk];
        }
        __syncthreads();
#pragma unroll
        for (int kk = 0; kk < BKK; kk++) {
            float a[4], w[4];
#pragma unroll
            for (int i = 0; i < 4; i++) a[i] = As[kk][tr * 4 + i];
#pragma unroll
            for (int j = 0; j < 4; j++) w[j] = Ws[kk][tc * 4 + j];
#pragma unroll
            for (int i = 0; i < 4; i++)
#pragma unroll
                for (int j = 0; j < 4; j++) acc[i][j] += a[i] * w[j];
        }
        __syncthreads();
    }
#pragma unroll
    for (int i = 0; i < 4; i++) {
        int m = bm + tr * 4 + i;
#pragma unroll
        for (int j = 0; j < 4; j++) {
            int n = bn + tc * 4 + j;
            float v = acc[i][j] + bias[n];
            if (act == 1) v = 0.5f * v * (1.0f + erff(v * 0.70710678118654752f));
            C[(size_t)m * N + n] = v;
        }
    }
}

// ---------------- attention: one block per (b, head, query-row) ------------
__global__ void attn_kernel(const float* __restrict__ qkv,  // (B*S, 3E)
                            float* __restrict__ ao,         // (B*S, E)
                            const int* __restrict__ tt_p,
                            const int* __restrict__ rtc_p) {
    int bid = blockIdx.x;            // B*H*S
    int i = bid & (SEQ - 1);
    int bh = bid >> 10;
    int hh = bh % NHEAD;
    int b = bh / NHEAD;
    int tid = threadIdx.x;           // 256
    int nt = *tt_p + 1;
    int rtc = *rtc_p;

    __shared__ float q[HDIM];
    __shared__ float sc[SEQ];
    __shared__ float red[256];

    const float* qrow = qkv + (size_t)(b * SEQ + i) * (3 * EMB) + hh * HDIM;
    if (tid < HDIM) q[tid] = qrow[tid];
    __syncthreads();

    const float scale = 0.125f;  // 1/sqrt(64)
    for (int j = tid; j < SEQ; j += 256) {
        int bi = i / nt, bj = j / nt;
        bool same = (bi == bj) && (bi < rtc) && ((i % nt) >= (j % nt));
        bool sv = ((j % nt) == 0) && (bj < rtc) && (i > j) && (i < rtc * nt);
        float s;
        if (same || sv) {
            const float* krow = qkv + (size_t)(b * SEQ + j) * (3 * EMB) + EMB + hh * HDIM;
            float dot = 0.0f;
#pragma unroll
            for (int d = 0; d < HDIM; d++) dot += q[d] * krow[d];
            s = dot * scale;
        } else {
            s = -INFINITY;
        }
        sc[j] = s;
    }
    __syncthreads();

    // row max
    float m = -INFINITY;
    for (int j = tid; j < SEQ; j += 256) m = fmaxf(m, sc[j]);
    red[tid] = m;
    __syncthreads();
    for (int s2 = 128; s2 > 0; s2 >>= 1) {
        if (tid < s2) red[tid] = fmaxf(red[tid], red[tid + s2]);
        __syncthreads();
    }
    m = red[0];
    __syncthreads();

    // exp + sum
    float lsum = 0.0f;
    for (int j = tid; j < SEQ; j += 256) {
        float e = expf(sc[j] - m);
        sc[j] = e;
        lsum += e;
    }
    red[tid] = lsum;
    __syncthreads();
    for (int s2 = 128; s2 > 0; s2 >>= 1) {
        if (tid < s2) red[tid] += red[tid + s2];
        __syncthreads();
    }
    float inv = 1.0f / red[0];
    __syncthreads();

    // ao[i, dd] = sum_j p_j * v[j, dd]
    int dd = tid & (HDIM - 1);
    int ch = tid >> 6;               // 4 chunks of 256 j's
    float part = 0.0f;
    for (int j = ch * 256; j < ch * 256 + 256; j++) {
        float p = sc[j];
        const float* vrow = qkv + (size_t)(b * SEQ + j) * (3 * EMB) + 2 * EMB + hh * HDIM;
        part += p * vrow[dd];
    }
    red[tid] = part;
    __syncthreads();
    if (tid < HDIM) {
        float sum = red[tid] + red[tid + 64] + red[tid + 128] + red[tid + 192];
        ao[(size_t)(b * SEQ + i) * EMB + hh * HDIM + dd] = sum * inv;
    }
}

// ---------------- residual add + LayerNorm (row = 768) ---------------------
__global__ void add_ln_kernel(const float* __restrict__ X,
                              const float* __restrict__ Y,   // may be null
                              const float* __restrict__ w,
                              const float* __restrict__ bsh,
                              float* __restrict__ out) {
    int row = blockIdx.x;
    int tid = threadIdx.x;           // 256; 3 elems each
    const float* xr = X + (size_t)row * EMB;
    float v[3];
    float s = 0.0f;
#pragma unroll
    for (int t = 0; t < 3; t++) {
        int e = tid + 256 * t;
        float val = xr[e];
        if (Y) val += Y[(size_t)row * EMB + e];
        v[t] = val;
        s += val;
    }
    __shared__ float red[256];
    red[tid] = s;
    __syncthreads();
    for (int k = 128; k > 0; k >>= 1) {
        if (tid < k) red[tid] += red[tid + k];
        __syncthreads();
    }
    float mu = red[0] / (float)EMB;
    __syncthreads();
    float s2 = 0.0f;
#pragma unroll
    for (int t = 0; t < 3; t++) {
        float d = v[t] - mu;
        s2 += d * d;
    }
    red[tid] = s2;
    __syncthreads();
    for (int k = 128; k > 0; k >>= 1) {
        if (tid < k) red[tid] += red[tid + k];
        __syncthreads();
    }
    float var = red[0] / (float)EMB;
    float inv = rsqrtf(var + 1e-5f);
#pragma unroll
    for (int t = 0; t < 3; t++) {
        int e = tid + 256 * t;
        out[(size_t)row * EMB + e] = (v[t] - mu) * inv * w[e] + bsh[e];
    }
}

extern "C" void kernel_launch(void* const* d_in, const int* in_sizes, int n_in,
                              void* d_out, int out_size, void* d_ws, size_t ws_size,
                              hipStream_t stream) {
    const float* x      = (const float*)d_in[0];
    // d_in[1]: padding_mask (unused by the reference layer)
    const float* tpe    = (const float*)d_in[2];
    const float* Wqkv   = (const float*)d_in[3];
    const float* bqkv   = (const float*)d_in[4];
    const float* W1     = (const float*)d_in[5];
    const float* b1     = (const float*)d_in[6];
    const float* W2     = (const float*)d_in[7];
    const float* b2     = (const float*)d_in[8];
    const float* ln1_w  = (const float*)d_in[9];
    const float* ln1_b  = (const float*)d_in[10];
    const float* ln2_w  = (const float*)d_in[11];
    const float* ln2_b  = (const float*)d_in[12];
    const float* lnf_w  = (const float*)d_in[13];
    const float* lnf_b  = (const float*)d_in[14];
    const int*   tt     = (const int*)d_in[15];
    const int*   rtc    = (const int*)d_in[16];
    float* out = (float*)d_out;

    float* h   = (float*)d_ws;                 // ROWS*EMB
    float* big = h + (size_t)ROWS * EMB;       // ROWS*3E (also reused for FF1: ROWS*FF)
    float* tmp = big + (size_t)ROWS * 3 * EMB; // ROWS*EMB

    embed_kernel<<<(BATCH * SEQ * EMB + 255) / 256, 256, 0, stream>>>(x, tpe, h, tt, rtc);

    for (int l = 0; l < NLAYER; l++) {
        const float* Wq = Wqkv + (size_t)l * 3 * EMB * EMB;
        const float* bq = bqkv + (size_t)l * 3 * EMB;
        const float* w1 = W1 + (size_t)l * FFDIM * EMB;
        const float* bb1 = b1 + (size_t)l * FFDIM;
        const float* w2 = W2 + (size_t)l * EMB * FFDIM;
        const float* bb2 = b2 + (size_t)l * EMB;

        // qkv = h @ Wqkv^T + bqkv  -> big (2048 x 2304)
        gemm_bias_act<<<dim3(3 * EMB / BN, ROWS / BM), 256, 0, stream>>>(
            h, Wq, bq, big, ROWS, 3 * EMB, EMB, 0);

        // attention -> tmp (2048 x 768)
        attn_kernel<<<BATCH * NHEAD * SEQ, 256, 0, stream>>>(big, tmp, tt, rtc);

        // h = LN(h + ao)
        add_ln_kernel<<<ROWS, 256, 0, stream>>>(h, tmp, ln1_w + l * EMB, ln1_b + l * EMB, h);

        // ff1 = gelu(h @ W1^T + b1) -> big (2048 x 2048)
        gemm_bias_act<<<dim3(FFDIM / BN, ROWS / BM), 256, 0, stream>>>(
            h, w1, bb1, big, ROWS, FFDIM, EMB, 1);

        // ff2 = ff1 @ W2^T + b2 -> tmp (2048 x 768)
        gemm_bias_act<<<dim3(EMB / BN, ROWS / BM), 256, 0, stream>>>(
            big, w2, bb2, tmp, ROWS, EMB, FFDIM, 0);

        // h = LN(h + ff2)
        add_ln_kernel<<<ROWS, 256, 0, stream>>>(h, tmp, ln2_w + l * EMB, ln2_b + l * EMB, h);
    }

    // final LN -> out
    add_ln_kernel<<<ROWS, 256, 0, stream>>>(h, (const float*)nullptr, lnf_w, lnf_b, out);
}

// Round 2
// 708.749 us; speedup vs baseline: 12.1889x; 12.1889x over previous
//
#include <hip/hip_runtime.h>
#include <math.h>

#define SEQ 1024
#define EMB 768
#define NHEAD 12
#define HDIM 64
#define NLAYER 4
#define FFDIM 2048
#define BATCH 2
#define ROWS (BATCH * SEQ)   // 2048

using f16 = _Float16;
using f16x4 = __attribute__((ext_vector_type(4))) _Float16;
using f16x8 = __attribute__((ext_vector_type(8))) _Float16;
using f32x4 = __attribute__((ext_vector_type(4))) float;

__device__ inline void gload16(const void* g, void* l) {
    __builtin_amdgcn_global_load_lds((const __attribute__((address_space(1))) unsigned*)g,
                                     (__attribute__((address_space(3))) unsigned*)l, 16, 0, 0);
}

// ---------------- embed: h = x + sinusoidal_pe + thought_pe ----------------
__global__ void embed_kernel(const float* __restrict__ x,
                             const float* __restrict__ tpe,
                             float* __restrict__ h32,
                             f16* __restrict__ h16,
                             const int* __restrict__ tt_p,
                             const int* __restrict__ rtc_p) {
    int idx = blockIdx.x * blockDim.x + threadIdx.x;  // over B*S*E
    if (idx >= BATCH * SEQ * EMB) return;
    int e = idx % EMB;
    int s = (idx / EMB) % SEQ;
    int nt = *tt_p + 1;
    int rtc = *rtc_p;
    float val;
    if (s < rtc * nt) {
        int p = s / nt;
        int t = s % nt;
        int i2 = e & ~1;
        double div = exp(-(double)i2 * log(10000.0) / (double)EMB);
        double ang = (double)p * div;
        float pe = (e & 1) ? (float)cos(ang) : (float)sin(ang);
        val = x[idx] + pe + tpe[t * EMB + e];
    } else {
        val = 0.0f;
    }
    h32[idx] = val;
    h16[idx] = (f16)val;
}

// ---------------- f32 -> f16 cast (weights) ---------------------------------
__global__ void cast_f32_f16(const float* __restrict__ in, f16* __restrict__ out, int n4) {
    int i = blockIdx.x * blockDim.x + threadIdx.x;
    if (i >= n4) return;
    float4 v = ((const float4*)in)[i];
    f16x4 o;
    o[0] = (f16)v.x; o[1] = (f16)v.y; o[2] = (f16)v.z; o[3] = (f16)v.w;
    ((f16x4*)out)[i] = o;
}

// ---------------- MFMA GEMM: C = A @ W^T + bias (A: MxK f16, W: NxK f16) ----
// 128x128 tile, BK=64, 4 waves (2x2 of 64x64), global_load_lds staging with
// pre-swizzled source (XOR slot^(row&7)) for conflict-free ds_read_b128.
template<int ACT, int OUTF16>
__global__ __launch_bounds__(256) void gemm_f16(const f16* __restrict__ A,
                                                const f16* __restrict__ W,
                                                const float* __restrict__ bias,
                                                float* __restrict__ Cf,
                                                f16* __restrict__ Ch,
                                                int M, int N, int K) {
    __shared__ f16 As[128 * 64];
    __shared__ f16 Ws[128 * 64];
    const int tid = threadIdx.x, lane = tid & 63, wave = tid >> 6;
    const int bm = blockIdx.y * 128, bn = blockIdx.x * 128;
    const int l15 = lane & 15, l16 = lane >> 4;
    const int wm = (wave >> 1) * 64, wn = (wave & 1) * 64;
    const int srow = lane >> 3, sslot = lane & 7;

    f32x4 acc[4][4];
#pragma unroll
    for (int mi = 0; mi < 4; mi++)
#pragma unroll
        for (int ni = 0; ni < 4; ni++) acc[mi][ni] = (f32x4){0.f, 0.f, 0.f, 0.f};

    for (int k0 = 0; k0 < K; k0 += 64) {
#pragma unroll
        for (int i = 0; i < 4; i++) {
            int R0 = wave * 32 + i * 8;
            int row = R0 + srow;
            int gs = (sslot ^ (row & 7)) << 3;
            gload16(A + (size_t)(bm + row) * K + k0 + gs, As + R0 * 64);
            gload16(W + (size_t)(bn + row) * K + k0 + gs, Ws + R0 * 64);
        }
        __syncthreads();
#pragma unroll
        for (int ks = 0; ks < 2; ks++) {
            int kslot = l16 + ks * 4;
            f16x8 a[4], b[4];
#pragma unroll
            for (int mi = 0; mi < 4; mi++) {
                int row = wm + mi * 16 + l15;
                a[mi] = *(const f16x8*)(As + row * 64 + ((kslot ^ (row & 7)) << 3));
            }
#pragma unroll
            for (int ni = 0; ni < 4; ni++) {
                int row = wn + ni * 16 + l15;
                b[ni] = *(const f16x8*)(Ws + row * 64 + ((kslot ^ (row & 7)) << 3));
            }
#pragma unroll
            for (int mi = 0; mi < 4; mi++)
#pragma unroll
                for (int ni = 0; ni < 4; ni++)
                    acc[mi][ni] = __builtin_amdgcn_mfma_f32_16x16x32_f16(a[mi], b[ni], acc[mi][ni], 0, 0, 0);
        }
        __syncthreads();
    }

#pragma unroll
    for (int ni = 0; ni < 4; ni++) {
        int n = bn + wn + ni * 16 + l15;
        float bv = bias[n];
#pragma unroll
        for (int mi = 0; mi < 4; mi++) {
#pragma unroll
            for (int r = 0; r < 4; r++) {
                int m = bm + wm + mi * 16 + l16 * 4 + r;
                float v = acc[mi][ni][r] + bv;
                if (ACT) v = 0.5f * v * (1.0f + erff(v * 0.70710678118654752f));
                if (OUTF16) Ch[(size_t)m * N + n] = (f16)v;
                else        Cf[(size_t)m * N + n] = v;
            }
        }
    }
}

// ---------------- flash attention, MFMA, block-causal mask ------------------
// grid: (S/64, B*NHEAD). block 256 = 4 waves; wave w owns q rows [q0+16w, +16).
__global__ __launch_bounds__(256) void attn_flash(const f16* __restrict__ qkv, // (B*S, 3E)
                                                  float* __restrict__ ao,      // (B*S, E)
                                                  const int* __restrict__ tt_p,
                                                  const int* __restrict__ rtc_p) {
    __shared__ f16 Qs[64 * 64];
    __shared__ f16 Ks[64 * 64];
    __shared__ f16 VT[64 * 64];   // transposed: [dim][key]
    __shared__ f16 Ps[4 * 16 * 64];

    const int qt = blockIdx.x, bh = blockIdx.y;
    const int b = bh / NHEAD, hh = bh % NHEAD;
    const int q0 = qt * 64;
    const int tid = threadIdx.x, lane = tid & 63, wave = tid >> 6;
    const int l15 = lane & 15, l16 = lane >> 4;
    const int nt = *tt_p + 1;
    const int rtc = *rtc_p;
    const size_t RS = 3 * EMB;

    // ---- stage Q tile (rows q0..q0+63, cols hh*64..+63) with swizzle ----
#pragma unroll
    for (int it = 0; it < 2; it++) {
        int task = tid + 256 * it;            // 0..511
        int row = task >> 3, slot = task & 7;
        f16x8 v = *(const f16x8*)(qkv + (size_t)(b * SEQ + q0 + row) * RS + hh * HDIM + slot * 8);
        *(f16x8*)(Qs + row * 64 + ((slot ^ (row & 7)) << 3)) = v;
    }
    __syncthreads();

    // hoist Q A-fragments
    f16x8 qa[2];
#pragma unroll
    for (int ks = 0; ks < 2; ks++) {
        int row = wave * 16 + l15;
        int kslot = l16 + ks * 4;
        qa[ks] = *(const f16x8*)(Qs + row * 64 + ((kslot ^ (row & 7)) << 3));
    }

    // per-lane softmax state: 4 q-rows (l16*4 + r)
    float mrow[4], lsum[4];
    f32x4 o[4];
#pragma unroll
    for (int r = 0; r < 4; r++) { mrow[r] = -1e30f; lsum[r] = 0.f; }
#pragma unroll
    for (int nf = 0; nf < 4; nf++) o[nf] = (f32x4){0.f, 0.f, 0.f, 0.f};

    // hoisted i-side mask terms
    int iglob[4], idiv[4], imod[4], iok[4];
#pragma unroll
    for (int r = 0; r < 4; r++) {
        int i = q0 + wave * 16 + l16 * 4 + r;
        iglob[r] = i; idiv[r] = i / nt; imod[r] = i % nt;
        iok[r] = (i < rtc * nt);
    }

    for (int jt = 0; jt <= qt; jt++) {
        const int j0 = jt * 64;
        __syncthreads();   // prior tile's reads done before overwrite
        // ---- stage K tile ----
#pragma unroll
        for (int it = 0; it < 2; it++) {
            int task = tid + 256 * it;
            int row = task >> 3, slot = task & 7;
            f16x8 v = *(const f16x8*)(qkv + (size_t)(b * SEQ + j0 + row) * RS + EMB + hh * HDIM + slot * 8);
            *(f16x8*)(Ks + row * 64 + ((slot ^ (row & 7)) << 3)) = v;
        }
        // ---- stage V transposed ----
        {
            int key = tid >> 2, dg = (tid & 3) * 16;
            const f16* src = qkv + (size_t)(b * SEQ + j0 + key) * RS + 2 * EMB + hh * HDIM + dg;
            f16x8 v0 = *(const f16x8*)(src);
            f16x8 v1 = *(const f16x8*)(src + 8);
#pragma unroll
            for (int d2 = 0; d2 < 16; d2++) {
                int dim = dg + d2;
                f16 val = (d2 < 8) ? v0[d2] : v1[d2 - 8];
                VT[dim * 64 + ((((key >> 3) ^ (dim & 7))) << 3) + (key & 7)] = val;
            }
        }
        __syncthreads();

        // ---- S = Q K^T (16q x 64k per wave) ----
        f32x4 s[4];
#pragma unroll
        for (int nf = 0; nf < 4; nf++) {
            s[nf] = (f32x4){0.f, 0.f, 0.f, 0.f};
#pragma unroll
            for (int ks = 0; ks < 2; ks++) {
                int row = nf * 16 + l15;
                int kslot = l16 + ks * 4;
                f16x8 kb = *(const f16x8*)(Ks + row * 64 + ((kslot ^ (row & 7)) << 3));
                s[nf] = __builtin_amdgcn_mfma_f32_16x16x32_f16(qa[ks], kb, s[nf], 0, 0, 0);
            }
        }

        // ---- mask + online softmax ----
        float p[4][4];
        float tmax[4] = {-1e30f, -1e30f, -1e30f, -1e30f};
#pragma unroll
        for (int nf = 0; nf < 4; nf++) {
            int j = j0 + nf * 16 + l15;
            int jd = j / nt, jm = j % nt;
#pragma unroll
            for (int r = 0; r < 4; r++) {
                bool same = (idiv[r] == jd) && (idiv[r] < rtc) && (imod[r] >= jm);
                bool sv   = (jm == 0) && (jd < rtc) && (iglob[r] > j) && iok[r];
                float val = (same || sv) ? s[nf][r] * 0.125f : -1e30f;
                p[nf][r] = val;
                tmax[r] = fmaxf(tmax[r], val);
            }
        }
#pragma unroll
        for (int r = 0; r < 4; r++) {
            tmax[r] = fmaxf(tmax[r], __shfl_xor(tmax[r], 1));
            tmax[r] = fmaxf(tmax[r], __shfl_xor(tmax[r], 2));
            tmax[r] = fmaxf(tmax[r], __shfl_xor(tmax[r], 4));
            tmax[r] = fmaxf(tmax[r], __shfl_xor(tmax[r], 8));
        }
        float alpha[4], rsum[4];
#pragma unroll
        for (int r = 0; r < 4; r++) {
            float mn = fmaxf(mrow[r], tmax[r]);
            alpha[r] = expf(mrow[r] - mn);   // mrow=-1e30 first tile -> 0 (mn real)
            mrow[r] = mn;
            rsum[r] = 0.f;
        }
#pragma unroll
        for (int nf = 0; nf < 4; nf++)
#pragma unroll
            for (int r = 0; r < 4; r++) {
                float e = expf(p[nf][r] - mrow[r]);
                p[nf][r] = e;
                rsum[r] += e;
            }
#pragma unroll
        for (int r = 0; r < 4; r++) {
            rsum[r] += __shfl_xor(rsum[r], 1);
            rsum[r] += __shfl_xor(rsum[r], 2);
            rsum[r] += __shfl_xor(rsum[r], 4);
            rsum[r] += __shfl_xor(rsum[r], 8);
            lsum[r] = lsum[r] * alpha[r] + rsum[r];
        }
#pragma unroll
        for (int nf = 0; nf < 4; nf++)
#pragma unroll
            for (int r = 0; r < 4; r++) o[nf][r] *= alpha[r];

        // ---- write P (f16) to per-wave LDS ----
        f16* P = Ps + wave * 16 * 64;
#pragma unroll
        for (int nf = 0; nf < 4; nf++)
#pragma unroll
            for (int r = 0; r < 4; r++) {
                int prow = l16 * 4 + r;
                int pcol = nf * 16 + l15;
                P[prow * 64 + (((pcol >> 3) ^ (prow & 7)) << 3) + (pcol & 7)] = (f16)p[nf][r];
            }
        __syncthreads();

        // ---- O += P @ V ----
#pragma unroll
        for (int ks = 0; ks < 2; ks++) {
            int kslot = l16 + ks * 4;
            int prow = l15;
            f16x8 pa = *(const f16x8*)(P + prow * 64 + ((kslot ^ (prow & 7)) << 3));
#pragma unroll
            for (int nf = 0; nf < 4; nf++) {
                int vrow = nf * 16 + l15;
                f16x8 vb = *(const f16x8*)(VT + vrow * 64 + ((kslot ^ (vrow & 7)) << 3));
                o[nf] = __builtin_amdgcn_mfma_f32_16x16x32_f16(pa, vb, o[nf], 0, 0, 0);
            }
        }
    }

    // ---- epilogue ----
#pragma unroll
    for (int r = 0; r < 4; r++) {
        float inv = (lsum[r] > 0.f) ? 1.0f / lsum[r] : 0.0f;
        int i = q0 + wave * 16 + l16 * 4 + r;
#pragma unroll
        for (int nf = 0; nf < 4; nf++) {
            int dim = nf * 16 + l15;
            ao[(size_t)(b * SEQ + i) * EMB + hh * HDIM + dim] = o[nf][r] * inv;
        }
    }
}

// ---------------- residual add + LayerNorm (row = 768), f32 + f16 out ------
__global__ void add_ln_kernel(const float* __restrict__ X,
                              const float* __restrict__ Y,   // may be null
                              const float* __restrict__ w,
                              const float* __restrict__ bsh,
                              float* __restrict__ out32,
                              f16* __restrict__ out16) {    // may be null
    int row = blockIdx.x;
    int tid = threadIdx.x;           // 256; 3 elems each
    const float* xr = X + (size_t)row * EMB;
    float v[3];
    float s = 0.0f;
#pragma unroll
    for (int t = 0; t < 3; t++) {
        int e = tid + 256 * t;
        float val = xr[e];
        if (Y) val += Y[(size_t)row * EMB + e];
        v[t] = val;
        s += val;
    }
    __shared__ float red[256];
    red[tid] = s;
    __syncthreads();
    for (int k = 128; k > 0; k >>= 1) {
        if (tid < k) red[tid] += red[tid + k];
        __syncthreads();
    }
    float mu = red[0] / (float)EMB;
    __syncthreads();
    float s2 = 0.0f;
#pragma unroll
    for (int t = 0; t < 3; t++) {
        float d = v[t] - mu;
        s2 += d * d;
    }
    red[tid] = s2;
    __syncthreads();
    for (int k = 128; k > 0; k >>= 1) {
        if (tid < k) red[tid] += red[tid + k];
        __syncthreads();
    }
    float var = red[0] / (float)EMB;
    float inv = rsqrtf(var + 1e-5f);
#pragma unroll
    for (int t = 0; t < 3; t++) {
        int e = tid + 256 * t;
        float r = (v[t] - mu) * inv * w[e] + bsh[e];
        out32[(size_t)row * EMB + e] = r;
        if (out16) out16[(size_t)row * EMB + e] = (f16)r;
    }
}

extern "C" void kernel_launch(void* const* d_in, const int* in_sizes, int n_in,
                              void* d_out, int out_size, void* d_ws, size_t ws_size,
                              hipStream_t stream) {
    const float* x      = (const float*)d_in[0];
    const float* tpe    = (const float*)d_in[2];
    const float* Wqkv   = (const float*)d_in[3];
    const float* bqkv   = (const float*)d_in[4];
    const float* W1     = (const float*)d_in[5];
    const float* b1     = (const float*)d_in[6];
    const float* W2     = (const float*)d_in[7];
    const float* b2     = (const float*)d_in[8];
    const float* ln1_w  = (const float*)d_in[9];
    const float* ln1_b  = (const float*)d_in[10];
    const float* ln2_w  = (const float*)d_in[11];
    const float* ln2_b  = (const float*)d_in[12];
    const float* lnf_w  = (const float*)d_in[13];
    const float* lnf_b  = (const float*)d_in[14];
    const int*   tt     = (const int*)d_in[15];
    const int*   rtc    = (const int*)d_in[16];
    float* out = (float*)d_out;

    char* wsp = (char*)d_ws;
    float* h32  = (float*)wsp;                                   // 6291456 B
    f16*   h16  = (f16*)(wsp + 6291456);                         // 3145728 B
    f16*   big  = (f16*)(wsp + 6291456 + 3145728);               // 9437184 B (qkv / ff1)
    float* tmp  = (float*)(wsp + 6291456 + 3145728 + 9437184);   // 6291456 B
    f16*   wbuf = (f16*)(wsp + 6291456 + 3145728 + 9437184 + 6291456); // 3538944 B

    embed_kernel<<<(BATCH * SEQ * EMB + 255) / 256, 256, 0, stream>>>(x, tpe, h32, h16, tt, rtc);

    for (int l = 0; l < NLAYER; l++) {
        const float* Wq  = Wqkv + (size_t)l * 3 * EMB * EMB;
        const float* bq  = bqkv + (size_t)l * 3 * EMB;
        const float* w1  = W1 + (size_t)l * FFDIM * EMB;
        const float* bb1 = b1 + (size_t)l * FFDIM;
        const float* w2  = W2 + (size_t)l * EMB * FFDIM;
        const float* bb2 = b2 + (size_t)l * EMB;

        // qkv = h @ Wqkv^T + bqkv -> big (f16)
        cast_f32_f16<<<(3 * EMB * EMB / 4 + 255) / 256, 256, 0, stream>>>(Wq, wbuf, 3 * EMB * EMB / 4);
        gemm_f16<0, 1><<<dim3(3 * EMB / 128, ROWS / 128), 256, 0, stream>>>(
            h16, wbuf, bq, nullptr, big, ROWS, 3 * EMB, EMB);

        // attention -> tmp (f32)
        attn_flash<<<dim3(SEQ / 64, BATCH * NHEAD), 256, 0, stream>>>(big, tmp, tt, rtc);

        // h = LN(h + ao)
        add_ln_kernel<<<ROWS, 256, 0, stream>>>(h32, tmp, ln1_w + l * EMB, ln1_b + l * EMB, h32, h16);

        // ff1 = gelu(h @ W1^T + b1) -> big (f16)
        cast_f32_f16<<<(FFDIM * EMB / 4 + 255) / 256, 256, 0, stream>>>(w1, wbuf, FFDIM * EMB / 4);
        gemm_f16<1, 1><<<dim3(FFDIM / 128, ROWS / 128), 256, 0, stream>>>(
            h16, wbuf, bb1, nullptr, big, ROWS, FFDIM, EMB);

        // ff2 = ff1 @ W2^T + b2 -> tmp (f32)
        cast_f32_f16<<<(EMB * FFDIM / 4 + 255) / 256, 256, 0, stream>>>(w2, wbuf, EMB * FFDIM / 4);
        gemm_f16<0, 0><<<dim3(EMB / 128, ROWS / 128), 256, 0, stream>>>(
            big, wbuf, bb2, tmp, nullptr, ROWS, EMB, FFDIM);

        // h = LN(h + ff2)
        add_ln_kernel<<<ROWS, 256, 0, stream>>>(h32, tmp, ln2_w + l * EMB, ln2_b + l * EMB, h32, h16);
    }

    add_ln_kernel<<<ROWS, 256, 0, stream>>>(h32, nullptr, lnf_w, lnf_b, out, nullptr);
}

// Round 3
// 651.344 us; speedup vs baseline: 13.2632x; 1.0881x over previous
//
#include <hip/hip_runtime.h>
#include <math.h>

#define SEQ 1024
#define EMB 768
#define NHEAD 12
#define HDIM 64
#define NLAYER 4
#define FFDIM 2048
#define BATCH 2
#define ROWS (BATCH * SEQ)   // 2048

using f16 = _Float16;
using f16x4 = __attribute__((ext_vector_type(4))) _Float16;
using f16x8 = __attribute__((ext_vector_type(8))) _Float16;
using f32x4 = __attribute__((ext_vector_type(4))) float;

__device__ inline void gload16(const void* g, void* l) {
    __builtin_amdgcn_global_load_lds((const __attribute__((address_space(1))) unsigned*)g,
                                     (__attribute__((address_space(3))) unsigned*)l, 16, 0, 0);
}

// ---------------- embed: h = x + sinusoidal_pe + thought_pe ----------------
__global__ void embed_kernel(const float* __restrict__ x,
                             const float* __restrict__ tpe,
                             float* __restrict__ h32,
                             f16* __restrict__ h16,
                             const int* __restrict__ tt_p,
                             const int* __restrict__ rtc_p) {
    int idx = blockIdx.x * blockDim.x + threadIdx.x;  // over B*S*E
    if (idx >= BATCH * SEQ * EMB) return;
    int e = idx % EMB;
    int s = (idx / EMB) % SEQ;
    int nt = *tt_p + 1;
    int rtc = *rtc_p;
    float val;
    if (s < rtc * nt) {
        int p = s / nt;
        int t = s % nt;
        int i2 = e & ~1;
        double div = exp(-(double)i2 * log(10000.0) / (double)EMB);
        double ang = (double)p * div;
        float pe = (e & 1) ? (float)cos(ang) : (float)sin(ang);
        val = x[idx] + pe + tpe[t * EMB + e];
    } else {
        val = 0.0f;
    }
    h32[idx] = val;
    h16[idx] = (f16)val;
}

// ---------------- fused per-layer weight cast (3 regions, 1 launch) --------
__global__ void cast3(const float* __restrict__ a, int na,
                      const float* __restrict__ b, int nb,
                      const float* __restrict__ c, int nc,
                      f16* __restrict__ out) {   // na/nb/nc in float4 units
    int total = na + nb + nc;
    for (int i = blockIdx.x * blockDim.x + threadIdx.x; i < total;
         i += gridDim.x * blockDim.x) {
        const float* src;
        int off;
        if (i < na)            { src = a; off = i; }
        else if (i < na + nb)  { src = b; off = i - na; }
        else                   { src = c; off = i - na - nb; }
        float4 v = ((const float4*)src)[off];
        f16x4 o;
        o[0] = (f16)v.x; o[1] = (f16)v.y; o[2] = (f16)v.z; o[3] = (f16)v.w;
        ((f16x4*)out)[i] = o;
    }
}

// ---------------- MFMA GEMM: C = A @ W^T + bias ------------------------------
// OUT: 0 = f32 out (Cf, stride N); 1 = f16 out w/ optional GELU (Ch, stride N);
//      2 = qkv split: Q,K (n<2E) -> Ch stride 2E; V (n>=2E) transposed -> vtg[b,h,d,s]
template<int ACT, int OUT>
__global__ __launch_bounds__(256) void gemm_f16(const f16* __restrict__ A,
                                                const f16* __restrict__ W,
                                                const float* __restrict__ bias,
                                                float* __restrict__ Cf,
                                                f16* __restrict__ Ch,
                                                f16* __restrict__ vtg,
                                                int M, int N, int K) {
    __shared__ f16 As[128 * 64];
    __shared__ f16 Ws[128 * 64];
    const int tid = threadIdx.x, lane = tid & 63, wave = tid >> 6;
    const int bm = blockIdx.y * 128, bn = blockIdx.x * 128;
    const int l15 = lane & 15, l16 = lane >> 4;
    const int wm = (wave >> 1) * 64, wn = (wave & 1) * 64;
    const int srow = lane >> 3, sslot = lane & 7;

    f32x4 acc[4][4];
#pragma unroll
    for (int mi = 0; mi < 4; mi++)
#pragma unroll
        for (int ni = 0; ni < 4; ni++) acc[mi][ni] = (f32x4){0.f, 0.f, 0.f, 0.f};

    for (int k0 = 0; k0 < K; k0 += 64) {
#pragma unroll
        for (int i = 0; i < 4; i++) {
            int R0 = wave * 32 + i * 8;
            int row = R0 + srow;
            int gs = (sslot ^ (row & 7)) << 3;
            gload16(A + (size_t)(bm + row) * K + k0 + gs, As + R0 * 64);
            gload16(W + (size_t)(bn + row) * K + k0 + gs, Ws + R0 * 64);
        }
        __syncthreads();
#pragma unroll
        for (int ks = 0; ks < 2; ks++) {
            int kslot = l16 + ks * 4;
            f16x8 a[4], b[4];
#pragma unroll
            for (int mi = 0; mi < 4; mi++) {
                int row = wm + mi * 16 + l15;
                a[mi] = *(const f16x8*)(As + row * 64 + ((kslot ^ (row & 7)) << 3));
            }
#pragma unroll
            for (int ni = 0; ni < 4; ni++) {
                int row = wn + ni * 16 + l15;
                b[ni] = *(const f16x8*)(Ws + row * 64 + ((kslot ^ (row & 7)) << 3));
            }
#pragma unroll
            for (int mi = 0; mi < 4; mi++)
#pragma unroll
                for (int ni = 0; ni < 4; ni++)
                    acc[mi][ni] = __builtin_amdgcn_mfma_f32_16x16x32_f16(a[mi], b[ni], acc[mi][ni], 0, 0, 0);
        }
        __syncthreads();
    }

#pragma unroll
    for (int ni = 0; ni < 4; ni++) {
        int nbase = bn + wn + ni * 16;
        int n = nbase + l15;
        float bv = bias[n];
        if (OUT != 2 || nbase < 2 * EMB) {
            int cstride = (OUT == 2) ? 2 * EMB : N;
#pragma unroll
            for (int mi = 0; mi < 4; mi++) {
#pragma unroll
                for (int r = 0; r < 4; r++) {
                    int m = bm + wm + mi * 16 + l16 * 4 + r;
                    float v = acc[mi][ni][r] + bv;
                    if (ACT) v = 0.5f * v * (1.0f + erff(v * 0.70710678118654752f));
                    if (OUT == 0) Cf[(size_t)m * cstride + n] = v;
                    else          Ch[(size_t)m * cstride + n] = (f16)v;
                }
            }
        } else {
            // V third: write transposed vtg[((b*H + h)*64 + d) * SEQ + s]
            int d = n - 2 * EMB;
            int hh = d >> 6, dd = d & 63;
#pragma unroll
            for (int mi = 0; mi < 4; mi++) {
                int m0 = bm + wm + mi * 16 + l16 * 4;
                int bb = m0 >> 10, s0 = m0 & (SEQ - 1);
                f16x4 pack;
#pragma unroll
                for (int r = 0; r < 4; r++) pack[r] = (f16)(acc[mi][ni][r] + bv);
                *(f16x4*)(vtg + ((size_t)((bb * NHEAD + hh) * HDIM + dd)) * SEQ + s0) = pack;
            }
        }
    }
}

// ---------------- flash attention, MFMA, block-causal mask ------------------
// grid: (S/64, B*NHEAD), qt reversed so long blocks start first.
__global__ __launch_bounds__(256) void attn_flash(const f16* __restrict__ qk,  // (B*S, 2E)
                                                  const f16* __restrict__ vtg, // (B,H,64,S)
                                                  float* __restrict__ ao,      // (B*S, E)
                                                  const int* __restrict__ tt_p,
                                                  const int* __restrict__ rtc_p) {
    __shared__ f16 Qs[64 * 64];
    __shared__ f16 Ks[64 * 64];
    __shared__ f16 VT[64 * 64];   // [dim][key], staged linear+swizzle from vtg
    __shared__ f16 Ps[4 * 16 * 64];

    const int qt = gridDim.x - 1 - blockIdx.x;
    const int bh = blockIdx.y;
    const int b = bh / NHEAD, hh = bh % NHEAD;
    const int q0 = qt * 64;
    const int tid = threadIdx.x, lane = tid & 63, wave = tid >> 6;
    const int l15 = lane & 15, l16 = lane >> 4;
    const int nt = *tt_p + 1;
    const int rtc = *rtc_p;
    const int RS = 2 * EMB;
    const f16* vth = vtg + (size_t)(b * NHEAD + hh) * HDIM * SEQ;

    // ---- stage Q tile via global_load_lds (pre-swizzled source) ----
#pragma unroll
    for (int it = 0; it < 2; it++) {
        int R0 = wave * 16 + it * 8;
        int row = R0 + (lane >> 3), slot = lane & 7;
        gload16(qk + (size_t)(b * SEQ + q0 + row) * RS + hh * HDIM + ((slot ^ (row & 7)) << 3),
                Qs + R0 * 64);
    }
    __syncthreads();

    // hoist Q A-fragments
    f16x8 qa[2];
#pragma unroll
    for (int ks = 0; ks < 2; ks++) {
        int row = wave * 16 + l15;
        int kslot = l16 + ks * 4;
        qa[ks] = *(const f16x8*)(Qs + row * 64 + ((kslot ^ (row & 7)) << 3));
    }

    float mrow[4], lsum[4];
    f32x4 o[4];
#pragma unroll
    for (int r = 0; r < 4; r++) { mrow[r] = -1e30f; lsum[r] = 0.f; }
#pragma unroll
    for (int nf = 0; nf < 4; nf++) o[nf] = (f32x4){0.f, 0.f, 0.f, 0.f};

    int iglob[4], idiv[4], imod[4], iok[4];
#pragma unroll
    for (int r = 0; r < 4; r++) {
        int i = q0 + wave * 16 + l16 * 4 + r;
        iglob[r] = i; idiv[r] = i / nt; imod[r] = i % nt;
        iok[r] = (i < rtc * nt);
    }

    for (int jt = 0; jt <= qt; jt++) {
        const int j0 = jt * 64;
        __syncthreads();   // prior tile's reads done before overwrite
        // ---- stage K tile + V^T tile (both linear gload16) ----
#pragma unroll
        for (int it = 0; it < 2; it++) {
            int R0 = wave * 16 + it * 8;
            int row = R0 + (lane >> 3), slot = lane & 7;
            int gs = (slot ^ (row & 7)) << 3;
            gload16(qk + (size_t)(b * SEQ + j0 + row) * RS + EMB + hh * HDIM + gs, Ks + R0 * 64);
            gload16(vth + (size_t)row * SEQ + j0 + gs, VT + R0 * 64);
        }
        __syncthreads();

        // ---- S = Q K^T (16q x 64k per wave) ----
        f32x4 s[4];
#pragma unroll
        for (int nf = 0; nf < 4; nf++) {
            s[nf] = (f32x4){0.f, 0.f, 0.f, 0.f};
#pragma unroll
            for (int ks = 0; ks < 2; ks++) {
                int row = nf * 16 + l15;
                int kslot = l16 + ks * 4;
                f16x8 kb = *(const f16x8*)(Ks + row * 64 + ((kslot ^ (row & 7)) << 3));
                s[nf] = __builtin_amdgcn_mfma_f32_16x16x32_f16(qa[ks], kb, s[nf], 0, 0, 0);
            }
        }

        // ---- mask + online softmax ----
        float p[4][4];
        float tmax[4] = {-1e30f, -1e30f, -1e30f, -1e30f};
#pragma unroll
        for (int nf = 0; nf < 4; nf++) {
            int j = j0 + nf * 16 + l15;
            int jd = j / nt, jm = j % nt;
#pragma unroll
            for (int r = 0; r < 4; r++) {
                bool same = (idiv[r] == jd) && (idiv[r] < rtc) && (imod[r] >= jm);
                bool sv   = (jm == 0) && (jd < rtc) && (iglob[r] > j) && iok[r];
                float val = (same || sv) ? s[nf][r] * 0.125f : -1e30f;
                p[nf][r] = val;
                tmax[r] = fmaxf(tmax[r], val);
            }
        }
#pragma unroll
        for (int r = 0; r < 4; r++) {
            tmax[r] = fmaxf(tmax[r], __shfl_xor(tmax[r], 1));
            tmax[r] = fmaxf(tmax[r], __shfl_xor(tmax[r], 2));
            tmax[r] = fmaxf(tmax[r], __shfl_xor(tmax[r], 4));
            tmax[r] = fmaxf(tmax[r], __shfl_xor(tmax[r], 8));
        }
        float alpha[4], rsum[4];
#pragma unroll
        for (int r = 0; r < 4; r++) {
            float mn = fmaxf(mrow[r], tmax[r]);
            alpha[r] = expf(mrow[r] - mn);
            mrow[r] = mn;
            rsum[r] = 0.f;
        }
#pragma unroll
        for (int nf = 0; nf < 4; nf++)
#pragma unroll
            for (int r = 0; r < 4; r++) {
                float e = expf(p[nf][r] - mrow[r]);
                p[nf][r] = e;
                rsum[r] += e;
            }
#pragma unroll
        for (int r = 0; r < 4; r++) {
            rsum[r] += __shfl_xor(rsum[r], 1);
            rsum[r] += __shfl_xor(rsum[r], 2);
            rsum[r] += __shfl_xor(rsum[r], 4);
            rsum[r] += __shfl_xor(rsum[r], 8);
            lsum[r] = lsum[r] * alpha[r] + rsum[r];
        }
#pragma unroll
        for (int nf = 0; nf < 4; nf++)
#pragma unroll
            for (int r = 0; r < 4; r++) o[nf][r] *= alpha[r];

        // ---- write P (f16) to per-wave LDS (no barrier needed: wave-local) ----
        f16* P = Ps + wave * 16 * 64;
#pragma unroll
        for (int nf = 0; nf < 4; nf++)
#pragma unroll
            for (int r = 0; r < 4; r++) {
                int prow = l16 * 4 + r;
                int pcol = nf * 16 + l15;
                P[prow * 64 + (((pcol >> 3) ^ (prow & 7)) << 3) + (pcol & 7)] = (f16)p[nf][r];
            }

        // ---- O += P @ V ----
#pragma unroll
        for (int ks = 0; ks < 2; ks++) {
            int kslot = l16 + ks * 4;
            int prow = l15;
            f16x8 pa = *(const f16x8*)(P + prow * 64 + ((kslot ^ (prow & 7)) << 3));
#pragma unroll
            for (int nf = 0; nf < 4; nf++) {
                int vrow = nf * 16 + l15;
                f16x8 vb = *(const f16x8*)(VT + vrow * 64 + ((kslot ^ (vrow & 7)) << 3));
                o[nf] = __builtin_amdgcn_mfma_f32_16x16x32_f16(pa, vb, o[nf], 0, 0, 0);
            }
        }
    }

    // ---- epilogue ----
#pragma unroll
    for (int r = 0; r < 4; r++) {
        float inv = (lsum[r] > 0.f) ? 1.0f / lsum[r] : 0.0f;
        int i = q0 + wave * 16 + l16 * 4 + r;
#pragma unroll
        for (int nf = 0; nf < 4; nf++) {
            int dim = nf * 16 + l15;
            ao[(size_t)(b * SEQ + i) * EMB + hh * HDIM + dim] = o[nf][r] * inv;
        }
    }
}

// ---------------- residual add + LayerNorm (row = 768), f32 + f16 out ------
__global__ void add_ln_kernel(const float* __restrict__ X,
                              const float* __restrict__ Y,   // may be null
                              const float* __restrict__ w,
                              const float* __restrict__ bsh,
                              float* __restrict__ out32,
                              f16* __restrict__ out16) {    // may be null
    int row = blockIdx.x;
    int tid = threadIdx.x;           // 256; 3 elems each
    const float* xr = X + (size_t)row * EMB;
    float v[3];
    float s = 0.0f;
#pragma unroll
    for (int t = 0; t < 3; t++) {
        int e = tid + 256 * t;
        float val = xr[e];
        if (Y) val += Y[(size_t)row * EMB + e];
        v[t] = val;
        s += val;
    }
    __shared__ float red[256];
    red[tid] = s;
    __syncthreads();
    for (int k = 128; k > 0; k >>= 1) {
        if (tid < k) red[tid] += red[tid + k];
        __syncthreads();
    }
    float mu = red[0] / (float)EMB;
    __syncthreads();
    float s2 = 0.0f;
#pragma unroll
    for (int t = 0; t < 3; t++) {
        float d = v[t] - mu;
        s2 += d * d;
    }
    red[tid] = s2;
    __syncthreads();
    for (int k = 128; k > 0; k >>= 1) {
        if (tid < k) red[tid] += red[tid + k];
        __syncthreads();
    }
    float var = red[0] / (float)EMB;
    float inv = rsqrtf(var + 1e-5f);
#pragma unroll
    for (int t = 0; t < 3; t++) {
        int e = tid + 256 * t;
        float r = (v[t] - mu) * inv * w[e] + bsh[e];
        out32[(size_t)row * EMB + e] = r;
        if (out16) out16[(size_t)row * EMB + e] = (f16)r;
    }
}

extern "C" void kernel_launch(void* const* d_in, const int* in_sizes, int n_in,
                              void* d_out, int out_size, void* d_ws, size_t ws_size,
                              hipStream_t stream) {
    const float* x      = (const float*)d_in[0];
    const float* tpe    = (const float*)d_in[2];
    const float* Wqkv   = (const float*)d_in[3];
    const float* bqkv   = (const float*)d_in[4];
    const float* W1     = (const float*)d_in[5];
    const float* b1     = (const float*)d_in[6];
    const float* W2     = (const float*)d_in[7];
    const float* b2     = (const float*)d_in[8];
    const float* ln1_w  = (const float*)d_in[9];
    const float* ln1_b  = (const float*)d_in[10];
    const float* ln2_w  = (const float*)d_in[11];
    const float* ln2_b  = (const float*)d_in[12];
    const float* lnf_w  = (const float*)d_in[13];
    const float* lnf_b  = (const float*)d_in[14];
    const int*   tt     = (const int*)d_in[15];
    const int*   rtc    = (const int*)d_in[16];
    float* out = (float*)d_out;

    // workspace layout (bytes)
    char* wsp = (char*)d_ws;
    float* h32  = (float*)wsp;                       // 6,291,456
    f16*   h16  = (f16*)(wsp + 6291456);             // 3,145,728
    f16*   act  = (f16*)(wsp + 9437184);             // 8,388,608 (qk 2048x1536 / ff1 2048x2048)
    f16*   vtg  = (f16*)(wsp + 17825792);            // 3,145,728 (B,H,64,S)
    float* tmp  = (float*)(wsp + 20971520);          // 6,291,456 (ao / ff2, f32)
    f16*   wbuf = (f16*)(wsp + 27262976);            // 9,830,400 (per-layer weights f16)

    const int na = 3 * EMB * EMB / 4;   // float4 units
    const int nb = FFDIM * EMB / 4;
    const int nc = EMB * FFDIM / 4;
    f16* wq16 = wbuf;
    f16* w116 = wbuf + (size_t)na * 4;
    f16* w216 = wbuf + (size_t)(na + nb) * 4;

    embed_kernel<<<(BATCH * SEQ * EMB + 255) / 256, 256, 0, stream>>>(x, tpe, h32, h16, tt, rtc);

    for (int l = 0; l < NLAYER; l++) {
        const float* Wq  = Wqkv + (size_t)l * 3 * EMB * EMB;
        const float* bq  = bqkv + (size_t)l * 3 * EMB;
        const float* w1  = W1 + (size_t)l * FFDIM * EMB;
        const float* bb1 = b1 + (size_t)l * FFDIM;
        const float* w2  = W2 + (size_t)l * EMB * FFDIM;
        const float* bb2 = b2 + (size_t)l * EMB;

        cast3<<<2048, 256, 0, stream>>>(Wq, na, w1, nb, w2, nc, wbuf);

        // qkv: Q,K -> act (stride 1536), V -> vtg transposed
        gemm_f16<0, 2><<<dim3(3 * EMB / 128, ROWS / 128), 256, 0, stream>>>(
            h16, wq16, bq, nullptr, act, vtg, ROWS, 3 * EMB, EMB);

        // attention -> tmp (f32)
        attn_flash<<<dim3(SEQ / 64, BATCH * NHEAD), 256, 0, stream>>>(act, vtg, tmp, tt, rtc);

        // h = LN(h + ao)
        add_ln_kernel<<<ROWS, 256, 0, stream>>>(h32, tmp, ln1_w + l * EMB, ln1_b + l * EMB, h32, h16);

        // ff1 = gelu(h @ W1^T + b1) -> act (f16, 2048x2048)
        gemm_f16<1, 1><<<dim3(FFDIM / 128, ROWS / 128), 256, 0, stream>>>(
            h16, w116, bb1, nullptr, act, nullptr, ROWS, FFDIM, EMB);

        // ff2 = ff1 @ W2^T + b2 -> tmp (f32)
        gemm_f16<0, 0><<<dim3(EMB / 128, ROWS / 128), 256, 0, stream>>>(
            act, w216, bb2, tmp, nullptr, nullptr, ROWS, EMB, FFDIM);

        // h = LN(h + ff2)
        add_ln_kernel<<<ROWS, 256, 0, stream>>>(h32, tmp, ln2_w + l * EMB, ln2_b + l * EMB, h32, h16);
    }

    add_ln_kernel<<<ROWS, 256, 0, stream>>>(h32, nullptr, lnf_w, lnf_b, out, nullptr);
}

// Round 4
// 564.604 us; speedup vs baseline: 15.3008x; 1.1536x over previous
//
#include <hip/hip_runtime.h>
#include <math.h>

#define SEQ 1024
#define EMB 768
#define NHEAD 12
#define HDIM 64
#define NLAYER 4
#define FFDIM 2048
#define BATCH 2
#define ROWS (BATCH * SEQ)   // 2048
#define BH (BATCH * NHEAD)   // 24
#define NCHUNK 4             // KV chunks of 4 tiles (256 keys)

using f16 = _Float16;
using f16x4 = __attribute__((ext_vector_type(4))) _Float16;
using f16x8 = __attribute__((ext_vector_type(8))) _Float16;
using f32x4 = __attribute__((ext_vector_type(4))) float;

__device__ inline void gload16(const void* g, void* l) {
    __builtin_amdgcn_global_load_lds((const __attribute__((address_space(1))) unsigned*)g,
                                     (__attribute__((address_space(3))) unsigned*)l, 16, 0, 0);
}

// ---------------- embed: h = x + sinusoidal_pe + thought_pe ----------------
__global__ void embed_kernel(const float* __restrict__ x,
                             const float* __restrict__ tpe,
                             float* __restrict__ h32,
                             f16* __restrict__ h16,
                             const int* __restrict__ tt_p,
                             const int* __restrict__ rtc_p) {
    int idx = blockIdx.x * blockDim.x + threadIdx.x;  // over B*S*E
    if (idx >= BATCH * SEQ * EMB) return;
    int e = idx % EMB;
    int s = (idx / EMB) % SEQ;
    int nt = *tt_p + 1;
    int rtc = *rtc_p;
    float val;
    if (s < rtc * nt) {
        int p = s / nt;
        int t = s % nt;
        int i2 = e & ~1;
        float div = __expf((float)i2 * -0.0119926314f);  // -ln(10000)/768
        float ang = (float)p * div;
        float pe = (e & 1) ? __cosf(ang) : __sinf(ang);
        val = x[idx] + pe + tpe[t * EMB + e];
    } else {
        val = 0.0f;
    }
    h32[idx] = val;
    h16[idx] = (f16)val;
}

// ---------------- fused per-layer weight cast (3 regions, 1 launch) --------
__global__ void cast3(const float* __restrict__ a, int na,
                      const float* __restrict__ b, int nb,
                      const float* __restrict__ c, int nc,
                      f16* __restrict__ out) {   // na/nb/nc in float4 units
    int total = na + nb + nc;
    for (int i = blockIdx.x * blockDim.x + threadIdx.x; i < total;
         i += gridDim.x * blockDim.x) {
        const float* src;
        int off;
        if (i < na)            { src = a; off = i; }
        else if (i < na + nb)  { src = b; off = i - na; }
        else                   { src = c; off = i - na - nb; }
        float4 v = ((const float4*)src)[off];
        f16x4 o;
        o[0] = (f16)v.x; o[1] = (f16)v.y; o[2] = (f16)v.z; o[3] = (f16)v.w;
        ((f16x4*)out)[i] = o;
    }
}

// ---------------- bias prefill for split-K output --------------------------
__global__ void fill_bias(float* __restrict__ out, const float* __restrict__ bias) {
    int idx = blockIdx.x * blockDim.x + threadIdx.x;   // float4 units over ROWS*EMB
    if (idx >= ROWS * EMB / 4) return;
    int n4 = idx % (EMB / 4);
    ((float4*)out)[idx] = ((const float4*)bias)[n4];
}

// ---------------- MFMA GEMM: C = A @ W^T + bias ------------------------------
// OUT: 0 = f32 out; 1 = f16 out (opt GELU); 2 = qkv split (Q,K f16 stride 2E,
//      V transposed -> vtg[b,h,d,s]); 3 = f32 atomicAdd (split-K, bias prefilled)
template<int ACT, int OUT>
__global__ __launch_bounds__(256) void gemm_f16(const f16* __restrict__ A,
                                                const f16* __restrict__ W,
                                                const float* __restrict__ bias,
                                                float* __restrict__ Cf,
                                                f16* __restrict__ Ch,
                                                f16* __restrict__ vtg,
                                                int M, int N, int K) {
    __shared__ f16 As[128 * 64];
    __shared__ f16 Ws[128 * 64];
    const int tid = threadIdx.x, lane = tid & 63, wave = tid >> 6;
    const int bm = blockIdx.y * 128, bn = blockIdx.x * 128;
    const int l15 = lane & 15, l16 = lane >> 4;
    const int wm = (wave >> 1) * 64, wn = (wave & 1) * 64;
    const int srow = lane >> 3, sslot = lane & 7;
    const int klen = K / gridDim.z;
    const int kbeg = blockIdx.z * klen, kend = kbeg + klen;

    f32x4 acc[4][4];
#pragma unroll
    for (int mi = 0; mi < 4; mi++)
#pragma unroll
        for (int ni = 0; ni < 4; ni++) acc[mi][ni] = (f32x4){0.f, 0.f, 0.f, 0.f};

    for (int k0 = kbeg; k0 < kend; k0 += 64) {
#pragma unroll
        for (int i = 0; i < 4; i++) {
            int R0 = wave * 32 + i * 8;
            int row = R0 + srow;
            int gs = (sslot ^ (row & 7)) << 3;
            gload16(A + (size_t)(bm + row) * K + k0 + gs, As + R0 * 64);
            gload16(W + (size_t)(bn + row) * K + k0 + gs, Ws + R0 * 64);
        }
        __syncthreads();
#pragma unroll
        for (int ks = 0; ks < 2; ks++) {
            int kslot = l16 + ks * 4;
            f16x8 a[4], b[4];
#pragma unroll
            for (int mi = 0; mi < 4; mi++) {
                int row = wm + mi * 16 + l15;
                a[mi] = *(const f16x8*)(As + row * 64 + ((kslot ^ (row & 7)) << 3));
            }
#pragma unroll
            for (int ni = 0; ni < 4; ni++) {
                int row = wn + ni * 16 + l15;
                b[ni] = *(const f16x8*)(Ws + row * 64 + ((kslot ^ (row & 7)) << 3));
            }
#pragma unroll
            for (int mi = 0; mi < 4; mi++)
#pragma unroll
                for (int ni = 0; ni < 4; ni++)
                    acc[mi][ni] = __builtin_amdgcn_mfma_f32_16x16x32_f16(a[mi], b[ni], acc[mi][ni], 0, 0, 0);
        }
        __syncthreads();
    }

#pragma unroll
    for (int ni = 0; ni < 4; ni++) {
        int nbase = bn + wn + ni * 16;
        int n = nbase + l15;
        if (OUT == 3) {
#pragma unroll
            for (int mi = 0; mi < 4; mi++)
#pragma unroll
                for (int r = 0; r < 4; r++) {
                    int m = bm + wm + mi * 16 + l16 * 4 + r;
                    atomicAdd(&Cf[(size_t)m * N + n], acc[mi][ni][r]);
                }
        } else {
            float bv = bias[n];
            if (OUT != 2 || nbase < 2 * EMB) {
                int cstride = (OUT == 2) ? 2 * EMB : N;
#pragma unroll
                for (int mi = 0; mi < 4; mi++) {
#pragma unroll
                    for (int r = 0; r < 4; r++) {
                        int m = bm + wm + mi * 16 + l16 * 4 + r;
                        float v = acc[mi][ni][r] + bv;
                        if (ACT) v = 0.5f * v * (1.0f + erff(v * 0.70710678118654752f));
                        if (OUT == 0) Cf[(size_t)m * cstride + n] = v;
                        else          Ch[(size_t)m * cstride + n] = (f16)v;
                    }
                }
            } else {
                // V third: write transposed vtg[((b*H + h)*64 + d) * SEQ + s]
                int d = n - 2 * EMB;
                int hh = d >> 6, dd = d & 63;
#pragma unroll
                for (int mi = 0; mi < 4; mi++) {
                    int m0 = bm + wm + mi * 16 + l16 * 4;
                    int bb = m0 >> 10, s0 = m0 & (SEQ - 1);
                    f16x4 pack;
#pragma unroll
                    for (int r = 0; r < 4; r++) pack[r] = (f16)(acc[mi][ni][r] + bv);
                    *(f16x4*)(vtg + ((size_t)((bb * NHEAD + hh) * HDIM + dd)) * SEQ + s0) = pack;
                }
            }
        }
    }
}

// ---------------- flash attention partials (split-KV) ------------------------
// grid: (NCHUNK, S/64, BH). Chunk c covers j-tiles [4c, min(4c+3, qt)].
__global__ __launch_bounds__(256) void attn_part(const f16* __restrict__ qk,  // (B*S, 2E)
                                                 const f16* __restrict__ vtg, // (B,H,64,S)
                                                 f16* __restrict__ po,        // [NCHUNK][BH][SEQ][64]
                                                 float* __restrict__ pm,      // [NCHUNK][BH][SEQ]
                                                 float* __restrict__ pl,
                                                 const int* __restrict__ tt_p,
                                                 const int* __restrict__ rtc_p) {
    const int c = blockIdx.x;
    const int qt = blockIdx.y;
    if (c * 4 > qt) return;
    const int bh = blockIdx.z;
    const int b = bh / NHEAD, hh = bh % NHEAD;
    const int q0 = qt * 64;
    const int jt_beg = c * 4, jt_end = min(qt, c * 4 + 3);

    __shared__ f16 Qs[64 * 64];
    __shared__ f16 Ks[64 * 64];
    __shared__ f16 VT[64 * 64];
    __shared__ f16 Ps[4 * 16 * 64];

    const int tid = threadIdx.x, lane = tid & 63, wave = tid >> 6;
    const int l15 = lane & 15, l16 = lane >> 4;
    const int nt = *tt_p + 1;
    const int rtc = *rtc_p;
    const int RS = 2 * EMB;
    const f16* vth = vtg + (size_t)(b * NHEAD + hh) * HDIM * SEQ;
    const float SCALE2 = 0.125f * 1.44269504088896f;   // scale * log2(e)

    // ---- stage Q tile (pre-swizzled source) ----
#pragma unroll
    for (int it = 0; it < 2; it++) {
        int R0 = wave * 16 + it * 8;
        int row = R0 + (lane >> 3), slot = lane & 7;
        gload16(qk + (size_t)(b * SEQ + q0 + row) * RS + hh * HDIM + ((slot ^ (row & 7)) << 3),
                Qs + R0 * 64);
    }
    __syncthreads();

    f16x8 qa[2];
#pragma unroll
    for (int ks = 0; ks < 2; ks++) {
        int row = wave * 16 + l15;
        int kslot = l16 + ks * 4;
        qa[ks] = *(const f16x8*)(Qs + row * 64 + ((kslot ^ (row & 7)) << 3));
    }

    float mrow[4], lsum[4];
    f32x4 o[4];
#pragma unroll
    for (int r = 0; r < 4; r++) { mrow[r] = -1e30f; lsum[r] = 0.f; }
#pragma unroll
    for (int nf = 0; nf < 4; nf++) o[nf] = (f32x4){0.f, 0.f, 0.f, 0.f};

    int iglob[4], idiv[4], imod[4], iok[4];
#pragma unroll
    for (int r = 0; r < 4; r++) {
        int i = q0 + wave * 16 + l16 * 4 + r;
        iglob[r] = i; idiv[r] = i / nt; imod[r] = i % nt;
        iok[r] = (i < rtc * nt);
    }

    for (int jt = jt_beg; jt <= jt_end; jt++) {
        const int j0 = jt * 64;
        __syncthreads();
#pragma unroll
        for (int it = 0; it < 2; it++) {
            int R0 = wave * 16 + it * 8;
            int row = R0 + (lane >> 3), slot = lane & 7;
            int gs = (slot ^ (row & 7)) << 3;
            gload16(qk + (size_t)(b * SEQ + j0 + row) * RS + EMB + hh * HDIM + gs, Ks + R0 * 64);
            gload16(vth + (size_t)row * SEQ + j0 + gs, VT + R0 * 64);
        }
        __syncthreads();

        // ---- S = Q K^T ----
        f32x4 s[4];
#pragma unroll
        for (int nf = 0; nf < 4; nf++) {
            s[nf] = (f32x4){0.f, 0.f, 0.f, 0.f};
#pragma unroll
            for (int ks = 0; ks < 2; ks++) {
                int row = nf * 16 + l15;
                int kslot = l16 + ks * 4;
                f16x8 kb = *(const f16x8*)(Ks + row * 64 + ((kslot ^ (row & 7)) << 3));
                s[nf] = __builtin_amdgcn_mfma_f32_16x16x32_f16(qa[ks], kb, s[nf], 0, 0, 0);
            }
        }

        // ---- mask + online softmax (base-2) ----
        float p[4][4];
        float tmax[4] = {-1e30f, -1e30f, -1e30f, -1e30f};
#pragma unroll
        for (int nf = 0; nf < 4; nf++) {
            int j = j0 + nf * 16 + l15;
            int jd = j / nt, jm = j % nt;
#pragma unroll
            for (int r = 0; r < 4; r++) {
                bool same = (idiv[r] == jd) && (idiv[r] < rtc) && (imod[r] >= jm);
                bool sv   = (jm == 0) && (jd < rtc) && (iglob[r] > j) && iok[r];
                float val = (same || sv) ? s[nf][r] * SCALE2 : -1e30f;
                p[nf][r] = val;
                tmax[r] = fmaxf(tmax[r], val);
            }
        }
#pragma unroll
        for (int r = 0; r < 4; r++) {
            tmax[r] = fmaxf(tmax[r], __shfl_xor(tmax[r], 1));
            tmax[r] = fmaxf(tmax[r], __shfl_xor(tmax[r], 2));
            tmax[r] = fmaxf(tmax[r], __shfl_xor(tmax[r], 4));
            tmax[r] = fmaxf(tmax[r], __shfl_xor(tmax[r], 8));
        }
        float alpha[4], rsum[4], meff[4];
#pragma unroll
        for (int r = 0; r < 4; r++) {
            float mn = fmaxf(mrow[r], tmax[r]);
            alpha[r] = exp2f(mrow[r] - mn);          // sentinel-safe: 0-0=0 -> 1 w/ lsum=0
            mrow[r] = mn;
            meff[r] = (mn <= -1e29f) ? 0.f : mn;     // all-masked tile -> p underflows to 0
            rsum[r] = 0.f;
        }
#pragma unroll
        for (int nf = 0; nf < 4; nf++)
#pragma unroll
            for (int r = 0; r < 4; r++) {
                float e = exp2f(p[nf][r] - meff[r]);
                p[nf][r] = e;
                rsum[r] += e;
            }
#pragma unroll
        for (int r = 0; r < 4; r++) {
            rsum[r] += __shfl_xor(rsum[r], 1);
            rsum[r] += __shfl_xor(rsum[r], 2);
            rsum[r] += __shfl_xor(rsum[r], 4);
            rsum[r] += __shfl_xor(rsum[r], 8);
            lsum[r] = lsum[r] * alpha[r] + rsum[r];
        }
#pragma unroll
        for (int nf = 0; nf < 4; nf++)
#pragma unroll
            for (int r = 0; r < 4; r++) o[nf][r] *= alpha[r];

        // ---- P -> per-wave LDS (wave-local, lgkm-ordered) ----
        f16* P = Ps + wave * 16 * 64;
#pragma unroll
        for (int nf = 0; nf < 4; nf++)
#pragma unroll
            for (int r = 0; r < 4; r++) {
                int prow = l16 * 4 + r;
                int pcol = nf * 16 + l15;
                P[prow * 64 + (((pcol >> 3) ^ (prow & 7)) << 3) + (pcol & 7)] = (f16)p[nf][r];
            }

        // ---- O += P @ V ----
#pragma unroll
        for (int ks = 0; ks < 2; ks++) {
            int kslot = l16 + ks * 4;
            int prow = l15;
            f16x8 pa = *(const f16x8*)(P + prow * 64 + ((kslot ^ (prow & 7)) << 3));
#pragma unroll
            for (int nf = 0; nf < 4; nf++) {
                int vrow = nf * 16 + l15;
                f16x8 vb = *(const f16x8*)(VT + vrow * 64 + ((kslot ^ (vrow & 7)) << 3));
                o[nf] = __builtin_amdgcn_mfma_f32_16x16x32_f16(pa, vb, o[nf], 0, 0, 0);
            }
        }
    }

    // ---- write partials (unnormalized) ----
    const size_t base = (size_t)(c * BH + bh) * SEQ;
#pragma unroll
    for (int r = 0; r < 4; r++) {
        int i = q0 + wave * 16 + l16 * 4 + r;
#pragma unroll
        for (int nf = 0; nf < 4; nf++)
            po[(base + i) * 64 + nf * 16 + l15] = (f16)o[nf][r];
        if (l15 == 0) {
            pm[base + i] = mrow[r];
            pl[base + i] = lsum[r];
        }
    }
}

// ---------------- combine partials -> ao -----------------------------------
// grid: (SEQ/4, BH), 256 threads: 4 rows x 64 dims.
__global__ __launch_bounds__(256) void attn_comb(const f16* __restrict__ po,
                                                 const float* __restrict__ pm,
                                                 const float* __restrict__ pl,
                                                 float* __restrict__ ao) {
    const int bh = blockIdx.y;
    const int i = blockIdx.x * 4 + (threadIdx.x >> 6);
    const int d = threadIdx.x & 63;
    const int b = bh / NHEAD, hh = bh % NHEAD;
    const int nch = (i >> 6) / 4 + 1;

    float m = -1e30f;
    for (int c = 0; c < nch; c++) m = fmaxf(m, pm[(size_t)(c * BH + bh) * SEQ + i]);
    float meff = (m <= -1e29f) ? 0.f : m;
    float lt = 0.f, ot = 0.f;
    for (int c = 0; c < nch; c++) {
        size_t idx = (size_t)(c * BH + bh) * SEQ + i;
        float w = exp2f(pm[idx] - meff);
        lt += pl[idx] * w;
        ot += (float)po[idx * 64 + d] * w;
    }
    float inv = (lt > 0.f) ? 1.0f / lt : 0.0f;
    ao[(size_t)(b * SEQ + i) * EMB + hh * HDIM + d] = ot * inv;
}

// ---------------- residual add + LayerNorm, wave-per-row --------------------
__global__ __launch_bounds__(256) void add_ln_kernel(const float* __restrict__ X,
                                                     const float* __restrict__ Y,  // may be null
                                                     const float* __restrict__ w,
                                                     const float* __restrict__ bsh,
                                                     float* __restrict__ out32,
                                                     f16* __restrict__ out16) {   // may be null
    const int row = blockIdx.x * 4 + (threadIdx.x >> 6);
    const int lane = threadIdx.x & 63;
    const float* xr = X + (size_t)row * EMB;
    float4 v[3];
    float s = 0.f;
#pragma unroll
    for (int t = 0; t < 3; t++) {
        int e = t * 256 + lane * 4;
        float4 a = *(const float4*)(xr + e);
        if (Y) {
            float4 yv = *(const float4*)(Y + (size_t)row * EMB + e);
            a.x += yv.x; a.y += yv.y; a.z += yv.z; a.w += yv.w;
        }
        v[t] = a;
        s += a.x + a.y + a.z + a.w;
    }
#pragma unroll
    for (int k = 1; k < 64; k <<= 1) s += __shfl_xor(s, k);
    float mu = s * (1.0f / EMB);
    float s2 = 0.f;
#pragma unroll
    for (int t = 0; t < 3; t++) {
        float dx = v[t].x - mu, dy = v[t].y - mu, dz = v[t].z - mu, dw = v[t].w - mu;
        s2 += dx * dx + dy * dy + dz * dz + dw * dw;
    }
#pragma unroll
    for (int k = 1; k < 64; k <<= 1) s2 += __shfl_xor(s2, k);
    float inv = rsqrtf(s2 * (1.0f / EMB) + 1e-5f);
#pragma unroll
    for (int t = 0; t < 3; t++) {
        int e = t * 256 + lane * 4;
        float4 wv = *(const float4*)(w + e);
        float4 bv = *(const float4*)(bsh + e);
        float4 o;
        o.x = (v[t].x - mu) * inv * wv.x + bv.x;
        o.y = (v[t].y - mu) * inv * wv.y + bv.y;
        o.z = (v[t].z - mu) * inv * wv.z + bv.z;
        o.w = (v[t].w - mu) * inv * wv.w + bv.w;
        *(float4*)(out32 + (size_t)row * EMB + e) = o;
        if (out16) {
            f16x4 hh;
            hh[0] = (f16)o.x; hh[1] = (f16)o.y; hh[2] = (f16)o.z; hh[3] = (f16)o.w;
            *(f16x4*)(out16 + (size_t)row * EMB + e) = hh;
        }
    }
}

extern "C" void kernel_launch(void* const* d_in, const int* in_sizes, int n_in,
                              void* d_out, int out_size, void* d_ws, size_t ws_size,
                              hipStream_t stream) {
    const float* x      = (const float*)d_in[0];
    const float* tpe    = (const float*)d_in[2];
    const float* Wqkv   = (const float*)d_in[3];
    const float* bqkv   = (const float*)d_in[4];
    const float* W1     = (const float*)d_in[5];
    const float* b1     = (const float*)d_in[6];
    const float* W2     = (const float*)d_in[7];
    const float* b2     = (const float*)d_in[8];
    const float* ln1_w  = (const float*)d_in[9];
    const float* ln1_b  = (const float*)d_in[10];
    const float* ln2_w  = (const float*)d_in[11];
    const float* ln2_b  = (const float*)d_in[12];
    const float* lnf_w  = (const float*)d_in[13];
    const float* lnf_b  = (const float*)d_in[14];
    const int*   tt     = (const int*)d_in[15];
    const int*   rtc    = (const int*)d_in[16];
    float* out = (float*)d_out;

    // workspace layout (bytes)
    char* wsp = (char*)d_ws;
    float* h32  = (float*)wsp;                       //  6,291,456
    f16*   h16  = (f16*)(wsp + 6291456);             //  3,145,728
    f16*   act  = (f16*)(wsp + 9437184);             //  8,388,608 (qk 2048x1536 / ff1 2048x2048)
    f16*   vtg  = (f16*)(wsp + 17825792);            //  3,145,728 (B,H,64,S)
    float* tmp  = (float*)(wsp + 20971520);          //  6,291,456 (ao / ff2, f32)
    f16*   wbuf = (f16*)(wsp + 27262976);            //  9,830,400 (per-layer weights f16)
    f16*   po   = (f16*)(wsp + 37093376);            // 12,582,912 (4*24*1024*64 f16)
    float* pm   = (float*)(wsp + 49676288);          //    393,216
    float* pl   = (float*)(wsp + 50069504);          //    393,216  -> total 50,462,720

    const int na = 3 * EMB * EMB / 4;   // float4 units
    const int nb = FFDIM * EMB / 4;
    const int nc = EMB * FFDIM / 4;
    f16* wq16 = wbuf;
    f16* w116 = wbuf + (size_t)na * 4;
    f16* w216 = wbuf + (size_t)(na + nb) * 4;

    embed_kernel<<<(BATCH * SEQ * EMB + 255) / 256, 256, 0, stream>>>(x, tpe, h32, h16, tt, rtc);

    for (int l = 0; l < NLAYER; l++) {
        const float* Wq  = Wqkv + (size_t)l * 3 * EMB * EMB;
        const float* bq  = bqkv + (size_t)l * 3 * EMB;
        const float* w1  = W1 + (size_t)l * FFDIM * EMB;
        const float* bb1 = b1 + (size_t)l * FFDIM;
        const float* w2  = W2 + (size_t)l * EMB * FFDIM;
        const float* bb2 = b2 + (size_t)l * EMB;

        cast3<<<2048, 256, 0, stream>>>(Wq, na, w1, nb, w2, nc, wbuf);

        // qkv: Q,K -> act (stride 1536), V -> vtg transposed
        gemm_f16<0, 2><<<dim3(3 * EMB / 128, ROWS / 128), 256, 0, stream>>>(
            h16, wq16, bq, nullptr, act, vtg, ROWS, 3 * EMB, EMB);

        // attention: partials then combine -> tmp (f32)
        attn_part<<<dim3(NCHUNK, SEQ / 64, BH), 256, 0, stream>>>(act, vtg, po, pm, pl, tt, rtc);
        attn_comb<<<dim3(SEQ / 4, BH), 256, 0, stream>>>(po, pm, pl, tmp);

        // h = LN(h + ao)
        add_ln_kernel<<<ROWS / 4, 256, 0, stream>>>(h32, tmp, ln1_w + l * EMB, ln1_b + l * EMB, h32, h16);

        // ff1 = gelu(h @ W1^T + b1) -> act (f16, 2048x2048)
        gemm_f16<1, 1><<<dim3(FFDIM / 128, ROWS / 128), 256, 0, stream>>>(
            h16, w116, bb1, nullptr, act, nullptr, ROWS, FFDIM, EMB);

        // ff2 = ff1 @ W2^T + b2 -> tmp (f32), split-K x2 with bias prefill
        fill_bias<<<(ROWS * EMB / 4 + 255) / 256, 256, 0, stream>>>(tmp, bb2);
        gemm_f16<0, 3><<<dim3(EMB / 128, ROWS / 128, 2), 256, 0, stream>>>(
            act, w216, bb2, tmp, nullptr, nullptr, ROWS, EMB, FFDIM);

        // h = LN(h + ff2)
        add_ln_kernel<<<ROWS / 4, 256, 0, stream>>>(h32, tmp, ln2_w + l * EMB, ln2_b + l * EMB, h32, h16);
    }

    add_ln_kernel<<<ROWS / 4, 256, 0, stream>>>(h32, nullptr, lnf_w, lnf_b, out, nullptr);
}

// Round 5
// 490.647 us; speedup vs baseline: 17.6072x; 1.1507x over previous
//
#include <hip/hip_runtime.h>
#include <math.h>

#define SEQ 1024
#define EMB 768
#define NHEAD 12
#define HDIM 64
#define NLAYER 4
#define FFDIM 2048
#define BATCH 2
#define ROWS (BATCH * SEQ)   // 2048
#define BH (BATCH * NHEAD)   // 24
#define NCHUNK 4             // KV chunks of 4 tiles (256 keys)

using f16 = _Float16;
using f16x4 = __attribute__((ext_vector_type(4))) _Float16;
using f16x8 = __attribute__((ext_vector_type(8))) _Float16;
using f32x4 = __attribute__((ext_vector_type(4))) float;

__device__ inline void gload16(const void* g, void* l) {
    __builtin_amdgcn_global_load_lds((const __attribute__((address_space(1))) unsigned*)g,
                                     (__attribute__((address_space(3))) unsigned*)l, 16, 0, 0);
}

// ---------------- embed: h = x + sinusoidal_pe + thought_pe ----------------
__global__ void embed_kernel(const float* __restrict__ x,
                             const float* __restrict__ tpe,
                             float* __restrict__ h32,
                             f16* __restrict__ h16,
                             const int* __restrict__ tt_p,
                             const int* __restrict__ rtc_p) {
    int idx = blockIdx.x * blockDim.x + threadIdx.x;  // over B*S*E
    if (idx >= BATCH * SEQ * EMB) return;
    int e = idx % EMB;
    int s = (idx / EMB) % SEQ;
    int nt = *tt_p + 1;
    int rtc = *rtc_p;
    float val;
    if (s < rtc * nt) {
        int p = s / nt;
        int t = s % nt;
        int i2 = e & ~1;
        float div = __expf((float)i2 * -0.0119926314f);  // -ln(10000)/768
        float ang = (float)p * div;
        float pe = (e & 1) ? __cosf(ang) : __sinf(ang);
        val = x[idx] + pe + tpe[t * EMB + e];
    } else {
        val = 0.0f;
    }
    h32[idx] = val;
    h16[idx] = (f16)val;
}

// ---------------- all-layer weight cast (3 contiguous regions, 1 launch) ----
__global__ void cast3(const float* __restrict__ a, int na,
                      const float* __restrict__ b, int nb,
                      const float* __restrict__ c, int nc,
                      f16* __restrict__ oa, f16* __restrict__ ob, f16* __restrict__ oc) {
    int total = na + nb + nc;   // float4 units
    for (int i = blockIdx.x * blockDim.x + threadIdx.x; i < total;
         i += gridDim.x * blockDim.x) {
        const float* src;
        f16* dst;
        int off;
        if (i < na)            { src = a; dst = oa; off = i; }
        else if (i < na + nb)  { src = b; dst = ob; off = i - na; }
        else                   { src = c; dst = oc; off = i - na - nb; }
        float4 v = ((const float4*)src)[off];
        f16x4 o;
        o[0] = (f16)v.x; o[1] = (f16)v.y; o[2] = (f16)v.z; o[3] = (f16)v.w;
        ((f16x4*)dst)[off] = o;
    }
}

// ---------------- MFMA GEMM: C = A @ W^T (+ bias) ----------------------------
// OUT: 1 = f16 out (+bias, opt GELU); 2 = qkv split (Q,K f16 stride 2E +bias,
//      V transposed +bias -> vtg[b,h,d,s]); 3 = f32 plain store of raw acc to
//      Cf + z*ROWS*N (split-K partials; bias added downstream)
template<int ACT, int OUT>
__global__ __launch_bounds__(256) void gemm_f16(const f16* __restrict__ A,
                                                const f16* __restrict__ W,
                                                const float* __restrict__ bias,
                                                float* __restrict__ Cf,
                                                f16* __restrict__ Ch,
                                                f16* __restrict__ vtg,
                                                int M, int N, int K) {
    __shared__ f16 As[128 * 64];
    __shared__ f16 Ws[128 * 64];
    const int tid = threadIdx.x, lane = tid & 63, wave = tid >> 6;
    const int bm = blockIdx.y * 128, bn = blockIdx.x * 128;
    const int l15 = lane & 15, l16 = lane >> 4;
    const int wm = (wave >> 1) * 64, wn = (wave & 1) * 64;
    const int srow = lane >> 3, sslot = lane & 7;
    const int klen = K / gridDim.z;
    const int kbeg = blockIdx.z * klen, kend = kbeg + klen;

    f32x4 acc[4][4];
#pragma unroll
    for (int mi = 0; mi < 4; mi++)
#pragma unroll
        for (int ni = 0; ni < 4; ni++) acc[mi][ni] = (f32x4){0.f, 0.f, 0.f, 0.f};

    for (int k0 = kbeg; k0 < kend; k0 += 64) {
#pragma unroll
        for (int i = 0; i < 4; i++) {
            int R0 = wave * 32 + i * 8;
            int row = R0 + srow;
            int gs = (sslot ^ (row & 7)) << 3;
            gload16(A + (size_t)(bm + row) * K + k0 + gs, As + R0 * 64);
            gload16(W + (size_t)(bn + row) * K + k0 + gs, Ws + R0 * 64);
        }
        __syncthreads();
#pragma unroll
        for (int ks = 0; ks < 2; ks++) {
            int kslot = l16 + ks * 4;
            f16x8 a[4], b[4];
#pragma unroll
            for (int mi = 0; mi < 4; mi++) {
                int row = wm + mi * 16 + l15;
                a[mi] = *(const f16x8*)(As + row * 64 + ((kslot ^ (row & 7)) << 3));
            }
#pragma unroll
            for (int ni = 0; ni < 4; ni++) {
                int row = wn + ni * 16 + l15;
                b[ni] = *(const f16x8*)(Ws + row * 64 + ((kslot ^ (row & 7)) << 3));
            }
#pragma unroll
            for (int mi = 0; mi < 4; mi++)
#pragma unroll
                for (int ni = 0; ni < 4; ni++)
                    acc[mi][ni] = __builtin_amdgcn_mfma_f32_16x16x32_f16(a[mi], b[ni], acc[mi][ni], 0, 0, 0);
        }
        __syncthreads();
    }

#pragma unroll
    for (int ni = 0; ni < 4; ni++) {
        int nbase = bn + wn + ni * 16;
        int n = nbase + l15;
        if (OUT == 3) {
            float* dst = Cf + (size_t)blockIdx.z * ROWS * N;
#pragma unroll
            for (int mi = 0; mi < 4; mi++)
#pragma unroll
                for (int r = 0; r < 4; r++) {
                    int m = bm + wm + mi * 16 + l16 * 4 + r;
                    dst[(size_t)m * N + n] = acc[mi][ni][r];
                }
        } else {
            float bv = bias[n];
            if (OUT != 2 || nbase < 2 * EMB) {
                int cstride = (OUT == 2) ? 2 * EMB : N;
#pragma unroll
                for (int mi = 0; mi < 4; mi++) {
#pragma unroll
                    for (int r = 0; r < 4; r++) {
                        int m = bm + wm + mi * 16 + l16 * 4 + r;
                        float v = acc[mi][ni][r] + bv;
                        if (ACT) v = 0.5f * v * (1.0f + erff(v * 0.70710678118654752f));
                        Ch[(size_t)m * cstride + n] = (f16)v;
                    }
                }
            } else {
                // V third: write transposed vtg[((b*H + h)*64 + d) * SEQ + s]
                int d = n - 2 * EMB;
                int hh = d >> 6, dd = d & 63;
#pragma unroll
                for (int mi = 0; mi < 4; mi++) {
                    int m0 = bm + wm + mi * 16 + l16 * 4;
                    int bb = m0 >> 10, s0 = m0 & (SEQ - 1);
                    f16x4 pack;
#pragma unroll
                    for (int r = 0; r < 4; r++) pack[r] = (f16)(acc[mi][ni][r] + bv);
                    *(f16x4*)(vtg + ((size_t)((bb * NHEAD + hh) * HDIM + dd)) * SEQ + s0) = pack;
                }
            }
        }
    }
}

// ---------------- flash attention partials (split-KV) ------------------------
// grid: (NCHUNK, S/64, BH). Chunk c covers j-tiles [4c, min(4c+3, qt)].
__global__ __launch_bounds__(256) void attn_part(const f16* __restrict__ qk,  // (B*S, 2E)
                                                 const f16* __restrict__ vtg, // (B,H,64,S)
                                                 f16* __restrict__ po,        // [NCHUNK][BH][SEQ][64]
                                                 float* __restrict__ pm,      // [NCHUNK][BH][SEQ]
                                                 float* __restrict__ pl,
                                                 const int* __restrict__ tt_p,
                                                 const int* __restrict__ rtc_p) {
    const int c = blockIdx.x;
    const int qt = blockIdx.y;
    if (c * 4 > qt) return;
    const int bh = blockIdx.z;
    const int b = bh / NHEAD, hh = bh % NHEAD;
    const int q0 = qt * 64;
    const int jt_beg = c * 4, jt_end = min(qt, c * 4 + 3);

    __shared__ f16 Qs[64 * 64];
    __shared__ f16 Ks[64 * 64];
    __shared__ f16 VT[64 * 64];
    __shared__ f16 Ps[4 * 16 * 64];

    const int tid = threadIdx.x, lane = tid & 63, wave = tid >> 6;
    const int l15 = lane & 15, l16 = lane >> 4;
    const int nt = *tt_p + 1;
    const int rtc = *rtc_p;
    const int RS = 2 * EMB;
    const f16* vth = vtg + (size_t)(b * NHEAD + hh) * HDIM * SEQ;
    const float SCALE2 = 0.125f * 1.44269504088896f;   // scale * log2(e)

    // ---- stage Q tile (pre-swizzled source) ----
#pragma unroll
    for (int it = 0; it < 2; it++) {
        int R0 = wave * 16 + it * 8;
        int row = R0 + (lane >> 3), slot = lane & 7;
        gload16(qk + (size_t)(b * SEQ + q0 + row) * RS + hh * HDIM + ((slot ^ (row & 7)) << 3),
                Qs + R0 * 64);
    }
    __syncthreads();

    f16x8 qa[2];
#pragma unroll
    for (int ks = 0; ks < 2; ks++) {
        int row = wave * 16 + l15;
        int kslot = l16 + ks * 4;
        qa[ks] = *(const f16x8*)(Qs + row * 64 + ((kslot ^ (row & 7)) << 3));
    }

    float mrow[4], lsum[4];
    f32x4 o[4];
#pragma unroll
    for (int r = 0; r < 4; r++) { mrow[r] = -1e30f; lsum[r] = 0.f; }
#pragma unroll
    for (int nf = 0; nf < 4; nf++) o[nf] = (f32x4){0.f, 0.f, 0.f, 0.f};

    int iglob[4], idiv[4], imod[4], iok[4];
#pragma unroll
    for (int r = 0; r < 4; r++) {
        int i = q0 + wave * 16 + l16 * 4 + r;
        iglob[r] = i; idiv[r] = i / nt; imod[r] = i % nt;
        iok[r] = (i < rtc * nt);
    }

    for (int jt = jt_beg; jt <= jt_end; jt++) {
        const int j0 = jt * 64;
        __syncthreads();
#pragma unroll
        for (int it = 0; it < 2; it++) {
            int R0 = wave * 16 + it * 8;
            int row = R0 + (lane >> 3), slot = lane & 7;
            int gs = (slot ^ (row & 7)) << 3;
            gload16(qk + (size_t)(b * SEQ + j0 + row) * RS + EMB + hh * HDIM + gs, Ks + R0 * 64);
            gload16(vth + (size_t)row * SEQ + j0 + gs, VT + R0 * 64);
        }
        __syncthreads();

        // ---- S = Q K^T ----
        f32x4 s[4];
#pragma unroll
        for (int nf = 0; nf < 4; nf++) {
            s[nf] = (f32x4){0.f, 0.f, 0.f, 0.f};
#pragma unroll
            for (int ks = 0; ks < 2; ks++) {
                int row = nf * 16 + l15;
                int kslot = l16 + ks * 4;
                f16x8 kb = *(const f16x8*)(Ks + row * 64 + ((kslot ^ (row & 7)) << 3));
                s[nf] = __builtin_amdgcn_mfma_f32_16x16x32_f16(qa[ks], kb, s[nf], 0, 0, 0);
            }
        }

        // ---- mask + online softmax (base-2) ----
        float p[4][4];
        float tmax[4] = {-1e30f, -1e30f, -1e30f, -1e30f};
#pragma unroll
        for (int nf = 0; nf < 4; nf++) {
            int j = j0 + nf * 16 + l15;
            int jd = j / nt, jm = j % nt;
#pragma unroll
            for (int r = 0; r < 4; r++) {
                bool same = (idiv[r] == jd) && (idiv[r] < rtc) && (imod[r] >= jm);
                bool sv   = (jm == 0) && (jd < rtc) && (iglob[r] > j) && iok[r];
                float val = (same || sv) ? s[nf][r] * SCALE2 : -1e30f;
                p[nf][r] = val;
                tmax[r] = fmaxf(tmax[r], val);
            }
        }
#pragma unroll
        for (int r = 0; r < 4; r++) {
            tmax[r] = fmaxf(tmax[r], __shfl_xor(tmax[r], 1));
            tmax[r] = fmaxf(tmax[r], __shfl_xor(tmax[r], 2));
            tmax[r] = fmaxf(tmax[r], __shfl_xor(tmax[r], 4));
            tmax[r] = fmaxf(tmax[r], __shfl_xor(tmax[r], 8));
        }
        float alpha[4], rsum[4], meff[4];
#pragma unroll
        for (int r = 0; r < 4; r++) {
            float mn = fmaxf(mrow[r], tmax[r]);
            alpha[r] = exp2f(mrow[r] - mn);
            mrow[r] = mn;
            meff[r] = (mn <= -1e29f) ? 0.f : mn;
            rsum[r] = 0.f;
        }
#pragma unroll
        for (int nf = 0; nf < 4; nf++)
#pragma unroll
            for (int r = 0; r < 4; r++) {
                float e = exp2f(p[nf][r] - meff[r]);
                p[nf][r] = e;
                rsum[r] += e;
            }
#pragma unroll
        for (int r = 0; r < 4; r++) {
            rsum[r] += __shfl_xor(rsum[r], 1);
            rsum[r] += __shfl_xor(rsum[r], 2);
            rsum[r] += __shfl_xor(rsum[r], 4);
            rsum[r] += __shfl_xor(rsum[r], 8);
            lsum[r] = lsum[r] * alpha[r] + rsum[r];
        }
#pragma unroll
        for (int nf = 0; nf < 4; nf++)
#pragma unroll
            for (int r = 0; r < 4; r++) o[nf][r] *= alpha[r];

        // ---- P -> per-wave LDS (wave-local, lgkm-ordered) ----
        f16* P = Ps + wave * 16 * 64;
#pragma unroll
        for (int nf = 0; nf < 4; nf++)
#pragma unroll
            for (int r = 0; r < 4; r++) {
                int prow = l16 * 4 + r;
                int pcol = nf * 16 + l15;
                P[prow * 64 + (((pcol >> 3) ^ (prow & 7)) << 3) + (pcol & 7)] = (f16)p[nf][r];
            }

        // ---- O += P @ V ----
#pragma unroll
        for (int ks = 0; ks < 2; ks++) {
            int kslot = l16 + ks * 4;
            int prow = l15;
            f16x8 pa = *(const f16x8*)(P + prow * 64 + ((kslot ^ (prow & 7)) << 3));
#pragma unroll
            for (int nf = 0; nf < 4; nf++) {
                int vrow = nf * 16 + l15;
                f16x8 vb = *(const f16x8*)(VT + vrow * 64 + ((kslot ^ (vrow & 7)) << 3));
                o[nf] = __builtin_amdgcn_mfma_f32_16x16x32_f16(pa, vb, o[nf], 0, 0, 0);
            }
        }
    }

    // ---- write partials (unnormalized) ----
    const size_t base = (size_t)(c * BH + bh) * SEQ;
#pragma unroll
    for (int r = 0; r < 4; r++) {
        int i = q0 + wave * 16 + l16 * 4 + r;
#pragma unroll
        for (int nf = 0; nf < 4; nf++)
            po[(base + i) * 64 + nf * 16 + l15] = (f16)o[nf][r];
        if (l15 == 0) {
            pm[base + i] = mrow[r];
            pl[base + i] = lsum[r];
        }
    }
}

// ---------------- LN( h + attn_combine(po,pm,pl) ), wave-per-row ------------
__global__ __launch_bounds__(256) void add_ln_attn(const float* __restrict__ X,
                                                   const f16* __restrict__ po,
                                                   const float* __restrict__ pm,
                                                   const float* __restrict__ pl,
                                                   const float* __restrict__ w,
                                                   const float* __restrict__ bsh,
                                                   float* __restrict__ out32,
                                                   f16* __restrict__ out16) {
    const int row = blockIdx.x * 4 + (threadIdx.x >> 6);
    const int lane = threadIdx.x & 63;
    const int b = row >> 10, i = row & (SEQ - 1);
    const int nch = (i >> 6) / 4 + 1;   // chunks with 4c <= qt
    const float* xr = X + (size_t)row * EMB;
    float4 v[3];
    float s = 0.f;
#pragma unroll
    for (int t = 0; t < 3; t++) {
        int e = t * 256 + lane * 4;
        int hh = e >> 6, d = e & 63;
        size_t hbase = (size_t)(b * NHEAD + hh) * SEQ + i;
        float m = -1e30f;
        for (int c = 0; c < nch; c++) m = fmaxf(m, pm[hbase + (size_t)c * BH * SEQ]);
        float meff = (m <= -1e29f) ? 0.f : m;
        float lt = 0.f;
        float4 ov = {0.f, 0.f, 0.f, 0.f};
        for (int c = 0; c < nch; c++) {
            size_t idx = hbase + (size_t)c * BH * SEQ;
            float wgt = exp2f(pm[idx] - meff);
            lt += pl[idx] * wgt;
            f16x4 pv = *(const f16x4*)(po + idx * 64 + d);
            ov.x += (float)pv[0] * wgt; ov.y += (float)pv[1] * wgt;
            ov.z += (float)pv[2] * wgt; ov.w += (float)pv[3] * wgt;
        }
        float inv = (lt > 0.f) ? 1.0f / lt : 0.0f;
        float4 a = *(const float4*)(xr + e);
        a.x += ov.x * inv; a.y += ov.y * inv; a.z += ov.z * inv; a.w += ov.w * inv;
        v[t] = a;
        s += a.x + a.y + a.z + a.w;
    }
#pragma unroll
    for (int k = 1; k < 64; k <<= 1) s += __shfl_xor(s, k);
    float mu = s * (1.0f / EMB);
    float s2 = 0.f;
#pragma unroll
    for (int t = 0; t < 3; t++) {
        float dx = v[t].x - mu, dy = v[t].y - mu, dz = v[t].z - mu, dw = v[t].w - mu;
        s2 += dx * dx + dy * dy + dz * dz + dw * dw;
    }
#pragma unroll
    for (int k = 1; k < 64; k <<= 1) s2 += __shfl_xor(s2, k);
    float inv = rsqrtf(s2 * (1.0f / EMB) + 1e-5f);
#pragma unroll
    for (int t = 0; t < 3; t++) {
        int e = t * 256 + lane * 4;
        float4 wv = *(const float4*)(w + e);
        float4 bv = *(const float4*)(bsh + e);
        float4 o;
        o.x = (v[t].x - mu) * inv * wv.x + bv.x;
        o.y = (v[t].y - mu) * inv * wv.y + bv.y;
        o.z = (v[t].z - mu) * inv * wv.z + bv.z;
        o.w = (v[t].w - mu) * inv * wv.w + bv.w;
        *(float4*)(out32 + (size_t)row * EMB + e) = o;
        f16x4 hh;
        hh[0] = (f16)o.x; hh[1] = (f16)o.y; hh[2] = (f16)o.z; hh[3] = (f16)o.w;
        *(f16x4*)(out16 + (size_t)row * EMB + e) = hh;
    }
}

// ---------------- LN( h + bias + sum of 4 split-K partials ) ----------------
__global__ __launch_bounds__(256) void add_ln_split4(const float* __restrict__ X,
                                                     const float* __restrict__ part, // 4x ROWS*EMB
                                                     const float* __restrict__ bias,
                                                     const float* __restrict__ w,
                                                     const float* __restrict__ bsh,
                                                     float* __restrict__ out32,
                                                     f16* __restrict__ out16) {
    const int row = blockIdx.x * 4 + (threadIdx.x >> 6);
    const int lane = threadIdx.x & 63;
    const float* xr = X + (size_t)row * EMB;
    float4 v[3];
    float s = 0.f;
#pragma unroll
    for (int t = 0; t < 3; t++) {
        int e = t * 256 + lane * 4;
        float4 a = *(const float4*)(xr + e);
        float4 bb = *(const float4*)(bias + e);
        a.x += bb.x; a.y += bb.y; a.z += bb.z; a.w += bb.w;
#pragma unroll
        for (int z = 0; z < 4; z++) {
            float4 pz = *(const float4*)(part + (size_t)z * ROWS * EMB + (size_t)row * EMB + e);
            a.x += pz.x; a.y += pz.y; a.z += pz.z; a.w += pz.w;
        }
        v[t] = a;
        s += a.x + a.y + a.z + a.w;
    }
#pragma unroll
    for (int k = 1; k < 64; k <<= 1) s += __shfl_xor(s, k);
    float mu = s * (1.0f / EMB);
    float s2 = 0.f;
#pragma unroll
    for (int t = 0; t < 3; t++) {
        float dx = v[t].x - mu, dy = v[t].y - mu, dz = v[t].z - mu, dw = v[t].w - mu;
        s2 += dx * dx + dy * dy + dz * dz + dw * dw;
    }
#pragma unroll
    for (int k = 1; k < 64; k <<= 1) s2 += __shfl_xor(s2, k);
    float inv = rsqrtf(s2 * (1.0f / EMB) + 1e-5f);
#pragma unroll
    for (int t = 0; t < 3; t++) {
        int e = t * 256 + lane * 4;
        float4 wv = *(const float4*)(w + e);
        float4 bv = *(const float4*)(bsh + e);
        float4 o;
        o.x = (v[t].x - mu) * inv * wv.x + bv.x;
        o.y = (v[t].y - mu) * inv * wv.y + bv.y;
        o.z = (v[t].z - mu) * inv * wv.z + bv.z;
        o.w = (v[t].w - mu) * inv * wv.w + bv.w;
        *(float4*)(out32 + (size_t)row * EMB + e) = o;
        f16x4 hh;
        hh[0] = (f16)o.x; hh[1] = (f16)o.y; hh[2] = (f16)o.z; hh[3] = (f16)o.w;
        *(f16x4*)(out16 + (size_t)row * EMB + e) = hh;
    }
}

// ---------------- plain final LN --------------------------------------------
__global__ __launch_bounds__(256) void ln_final(const float* __restrict__ X,
                                                const float* __restrict__ w,
                                                const float* __restrict__ bsh,
                                                float* __restrict__ out32) {
    const int row = blockIdx.x * 4 + (threadIdx.x >> 6);
    const int lane = threadIdx.x & 63;
    const float* xr = X + (size_t)row * EMB;
    float4 v[3];
    float s = 0.f;
#pragma unroll
    for (int t = 0; t < 3; t++) {
        int e = t * 256 + lane * 4;
        v[t] = *(const float4*)(xr + e);
        s += v[t].x + v[t].y + v[t].z + v[t].w;
    }
#pragma unroll
    for (int k = 1; k < 64; k <<= 1) s += __shfl_xor(s, k);
    float mu = s * (1.0f / EMB);
    float s2 = 0.f;
#pragma unroll
    for (int t = 0; t < 3; t++) {
        float dx = v[t].x - mu, dy = v[t].y - mu, dz = v[t].z - mu, dw = v[t].w - mu;
        s2 += dx * dx + dy * dy + dz * dz + dw * dw;
    }
#pragma unroll
    for (int k = 1; k < 64; k <<= 1) s2 += __shfl_xor(s2, k);
    float inv = rsqrtf(s2 * (1.0f / EMB) + 1e-5f);
#pragma unroll
    for (int t = 0; t < 3; t++) {
        int e = t * 256 + lane * 4;
        float4 wv = *(const float4*)(w + e);
        float4 bv = *(const float4*)(bsh + e);
        float4 o;
        o.x = (v[t].x - mu) * inv * wv.x + bv.x;
        o.y = (v[t].y - mu) * inv * wv.y + bv.y;
        o.z = (v[t].z - mu) * inv * wv.z + bv.z;
        o.w = (v[t].w - mu) * inv * wv.w + bv.w;
        *(float4*)(out32 + (size_t)row * EMB + e) = o;
    }
}

extern "C" void kernel_launch(void* const* d_in, const int* in_sizes, int n_in,
                              void* d_out, int out_size, void* d_ws, size_t ws_size,
                              hipStream_t stream) {
    const float* x      = (const float*)d_in[0];
    const float* tpe    = (const float*)d_in[2];
    const float* Wqkv   = (const float*)d_in[3];
    const float* bqkv   = (const float*)d_in[4];
    const float* W1     = (const float*)d_in[5];
    const float* b1     = (const float*)d_in[6];
    const float* W2     = (const float*)d_in[7];
    const float* b2     = (const float*)d_in[8];
    const float* ln1_w  = (const float*)d_in[9];
    const float* ln1_b  = (const float*)d_in[10];
    const float* ln2_w  = (const float*)d_in[11];
    const float* ln2_b  = (const float*)d_in[12];
    const float* lnf_w  = (const float*)d_in[13];
    const float* lnf_b  = (const float*)d_in[14];
    const int*   tt     = (const int*)d_in[15];
    const int*   rtc    = (const int*)d_in[16];
    float* out = (float*)d_out;

    // workspace layout (bytes)
    char* wsp = (char*)d_ws;
    float* h32  = (float*)wsp;                       //  6,291,456
    f16*   h16  = (f16*)(wsp + 6291456);             //  3,145,728
    f16*   act  = (f16*)(wsp + 9437184);             //  8,388,608 (qk 2048x1536 / ff1 2048x2048)
    f16*   vtg  = (f16*)(wsp + 17825792);            //  3,145,728 (B,H,64,S)
    float* part = (float*)(wsp + 20971520);          // 25,165,824 (4x ROWS*EMB f32)
    f16*   wbuf = (f16*)(wsp + 46137344);            // 39,321,600 (ALL layers f16 weights)
    f16*   po   = (f16*)(wsp + 85458944);            // 12,582,912
    float* pm   = (float*)(wsp + 98041856);          //    393,216
    float* pl   = (float*)(wsp + 98435072);          //    393,216  -> total 98,828,288

    const int EQ = 3 * EMB * EMB;      // per-layer Wqkv elems
    const int E1 = FFDIM * EMB;        // per-layer W1 elems
    const int E2 = EMB * FFDIM;        // per-layer W2 elems
    f16* wqAll = wbuf;
    f16* w1All = wbuf + (size_t)NLAYER * EQ;
    f16* w2All = w1All + (size_t)NLAYER * E1;

    // cast ALL layers' weights in one launch (sources are layer-contiguous)
    cast3<<<4096, 256, 0, stream>>>(Wqkv, NLAYER * EQ / 4, W1, NLAYER * E1 / 4,
                                    W2, NLAYER * E2 / 4, wqAll, w1All, w2All);

    embed_kernel<<<(BATCH * SEQ * EMB + 255) / 256, 256, 0, stream>>>(x, tpe, h32, h16, tt, rtc);

    for (int l = 0; l < NLAYER; l++) {
        const f16* wq16 = wqAll + (size_t)l * EQ;
        const f16* w116 = w1All + (size_t)l * E1;
        const f16* w216 = w2All + (size_t)l * E2;
        const float* bq  = bqkv + (size_t)l * 3 * EMB;
        const float* bb1 = b1 + (size_t)l * FFDIM;
        const float* bb2 = b2 + (size_t)l * EMB;

        // qkv: Q,K -> act (stride 1536), V -> vtg transposed
        gemm_f16<0, 2><<<dim3(3 * EMB / 128, ROWS / 128), 256, 0, stream>>>(
            h16, wq16, bq, nullptr, act, vtg, ROWS, 3 * EMB, EMB);

        // attention partials
        attn_part<<<dim3(NCHUNK, SEQ / 64, BH), 256, 0, stream>>>(act, vtg, po, pm, pl, tt, rtc);

        // h = LN(h + combine(po)) — combine fused into LN
        add_ln_attn<<<ROWS / 4, 256, 0, stream>>>(h32, po, pm, pl,
                                                  ln1_w + l * EMB, ln1_b + l * EMB, h32, h16);

        // ff1 = gelu(h @ W1^T + b1) -> act (f16, 2048x2048)
        gemm_f16<1, 1><<<dim3(FFDIM / 128, ROWS / 128), 256, 0, stream>>>(
            h16, w116, bb1, nullptr, act, nullptr, ROWS, FFDIM, EMB);

        // ff2 partials: raw acc -> part[z], split-K x4 (K chunk = 512)
        gemm_f16<0, 3><<<dim3(EMB / 128, ROWS / 128, 4), 256, 0, stream>>>(
            act, w216, nullptr, part, nullptr, nullptr, ROWS, EMB, FFDIM);

        // h = LN(h + b2 + sum(part)) — reduction fused into LN
        add_ln_split4<<<ROWS / 4, 256, 0, stream>>>(h32, part, bb2,
                                                    ln2_w + l * EMB, ln2_b + l * EMB, h32, h16);
    }

    ln_final<<<ROWS / 4, 256, 0, stream>>>(h32, lnf_w, lnf_b, out);
}

// Round 6
// 475.420 us; speedup vs baseline: 18.1711x; 1.0320x over previous
//
#include <hip/hip_runtime.h>
#include <math.h>

#define SEQ 1024
#define EMB 768
#define NHEAD 12
#define HDIM 64
#define NLAYER 4
#define FFDIM 2048
#define BATCH 2
#define ROWS (BATCH * SEQ)   // 2048
#define BH (BATCH * NHEAD)   // 24
#define NCHUNK 4             // KV chunks of 4 tiles (256 keys)

using f16 = _Float16;
using f16x4 = __attribute__((ext_vector_type(4))) _Float16;
using f16x8 = __attribute__((ext_vector_type(8))) _Float16;
using f32x4 = __attribute__((ext_vector_type(4))) float;
using f32x16 = __attribute__((ext_vector_type(16))) float;

__device__ inline void gload16(const void* g, void* l) {
    __builtin_amdgcn_global_load_lds((const __attribute__((address_space(1))) unsigned*)g,
                                     (__attribute__((address_space(3))) unsigned*)l, 16, 0, 0);
}

// ---------------- embed: h = x + sinusoidal_pe + thought_pe ----------------
__global__ void embed_kernel(const float* __restrict__ x,
                             const float* __restrict__ tpe,
                             float* __restrict__ h32,
                             f16* __restrict__ h16,
                             const int* __restrict__ tt_p,
                             const int* __restrict__ rtc_p) {
    int idx = blockIdx.x * blockDim.x + threadIdx.x;  // over B*S*E
    if (idx >= BATCH * SEQ * EMB) return;
    int e = idx % EMB;
    int s = (idx / EMB) % SEQ;
    int nt = *tt_p + 1;
    int rtc = *rtc_p;
    float val;
    if (s < rtc * nt) {
        int p = s / nt;
        int t = s % nt;
        int i2 = e & ~1;
        float div = __expf((float)i2 * -0.0119926314f);  // -ln(10000)/768
        float ang = (float)p * div;
        float pe = (e & 1) ? __cosf(ang) : __sinf(ang);
        val = x[idx] + pe + tpe[t * EMB + e];
    } else {
        val = 0.0f;
    }
    h32[idx] = val;
    h16[idx] = (f16)val;
}

// ---------------- all-layer weight cast (3 contiguous regions, 1 launch) ----
__global__ void cast3(const float* __restrict__ a, int na,
                      const float* __restrict__ b, int nb,
                      const float* __restrict__ c, int nc,
                      f16* __restrict__ oa, f16* __restrict__ ob, f16* __restrict__ oc) {
    int total = na + nb + nc;   // float4 units
    for (int i = blockIdx.x * blockDim.x + threadIdx.x; i < total;
         i += gridDim.x * blockDim.x) {
        const float* src;
        f16* dst;
        int off;
        if (i < na)            { src = a; dst = oa; off = i; }
        else if (i < na + nb)  { src = b; dst = ob; off = i - na; }
        else                   { src = c; dst = oc; off = i - na - nb; }
        float4 v = ((const float4*)src)[off];
        f16x4 o;
        o[0] = (f16)v.x; o[1] = (f16)v.y; o[2] = (f16)v.z; o[3] = (f16)v.w;
        ((f16x4*)dst)[off] = o;
    }
}

// ---------------- MFMA GEMM (32x32x16): C = A @ W^T (+ bias) -----------------
// OUT: 1 = f16 out (+bias, opt GELU); 2 = qkv split (Q,K f16 stride 2E +bias,
//      V transposed +bias -> vtg[b,h,d,s]); 3 = f32 plain store of raw acc to
//      Cf + z*ROWS*N (split-K partials; bias added downstream)
template<int ACT, int OUT>
__global__ __launch_bounds__(256) void gemm_f16(const f16* __restrict__ A,
                                                const f16* __restrict__ W,
                                                const float* __restrict__ bias,
                                                float* __restrict__ Cf,
                                                f16* __restrict__ Ch,
                                                f16* __restrict__ vtg,
                                                int M, int N, int K) {
    __shared__ f16 As[128 * 64];
    __shared__ f16 Ws[128 * 64];
    const int tid = threadIdx.x, lane = tid & 63, wave = tid >> 6;
    // XCD-aware block swizzle (bijective when nwg % 8 == 0)
    const int gx = gridDim.x;
    const int nwg = gx * gridDim.y;
    int orig = blockIdx.y * gx + blockIdx.x;
    int nid = (nwg & 7) ? orig : ((orig & 7) * (nwg >> 3) + (orig >> 3));
    const int bm = (nid / gx) * 128, bn = (nid % gx) * 128;
    const int l31 = lane & 31, l32 = lane >> 5;
    const int wm = (wave >> 1) * 64, wn = (wave & 1) * 64;
    const int srow = lane >> 3, sslot = lane & 7;
    const int klen = K / gridDim.z;
    const int kbeg = blockIdx.z * klen, kend = kbeg + klen;

    f32x16 acc[2][2];
#pragma unroll
    for (int mi = 0; mi < 2; mi++)
#pragma unroll
        for (int ni = 0; ni < 2; ni++)
#pragma unroll
            for (int e = 0; e < 16; e++) acc[mi][ni][e] = 0.f;

    for (int k0 = kbeg; k0 < kend; k0 += 64) {
#pragma unroll
        for (int i = 0; i < 4; i++) {
            int R0 = wave * 32 + i * 8;
            int row = R0 + srow;
            int gs = (sslot ^ (row & 7)) << 3;
            gload16(A + (size_t)(bm + row) * K + k0 + gs, As + R0 * 64);
            gload16(W + (size_t)(bn + row) * K + k0 + gs, Ws + R0 * 64);
        }
        __syncthreads();
#pragma unroll
        for (int ks = 0; ks < 4; ks++) {
            int kslot = ks * 2 + l32;   // 8 f16 k-elems per slot
            f16x8 a[2], b[2];
#pragma unroll
            for (int mi = 0; mi < 2; mi++) {
                int row = wm + mi * 32 + l31;
                a[mi] = *(const f16x8*)(As + row * 64 + ((kslot ^ (row & 7)) << 3));
            }
#pragma unroll
            for (int ni = 0; ni < 2; ni++) {
                int row = wn + ni * 32 + l31;
                b[ni] = *(const f16x8*)(Ws + row * 64 + ((kslot ^ (row & 7)) << 3));
            }
#pragma unroll
            for (int mi = 0; mi < 2; mi++)
#pragma unroll
                for (int ni = 0; ni < 2; ni++)
                    acc[mi][ni] = __builtin_amdgcn_mfma_f32_32x32x16_f16(a[mi], b[ni], acc[mi][ni], 0, 0, 0);
        }
        __syncthreads();
    }

    // epilogue: C row = (reg&3) + 8*(reg>>2) + 4*(lane>>5), col = lane&31
#pragma unroll
    for (int ni = 0; ni < 2; ni++) {
        int nbase = bn + wn + ni * 32;
        int n = nbase + l31;
        if (OUT == 3) {
            float* dst = Cf + (size_t)blockIdx.z * ROWS * N;
#pragma unroll
            for (int mi = 0; mi < 2; mi++)
#pragma unroll
                for (int reg = 0; reg < 16; reg++) {
                    int m = bm + wm + mi * 32 + (reg & 3) + 8 * (reg >> 2) + 4 * l32;
                    dst[(size_t)m * N + n] = acc[mi][ni][reg];
                }
        } else {
            float bv = bias[n];
            if (OUT != 2 || nbase < 2 * EMB) {
                int cstride = (OUT == 2) ? 2 * EMB : N;
#pragma unroll
                for (int mi = 0; mi < 2; mi++) {
#pragma unroll
                    for (int reg = 0; reg < 16; reg++) {
                        int m = bm + wm + mi * 32 + (reg & 3) + 8 * (reg >> 2) + 4 * l32;
                        float v = acc[mi][ni][reg] + bv;
                        if (ACT) v = 0.5f * v * (1.0f + erff(v * 0.70710678118654752f));
                        Ch[(size_t)m * cstride + n] = (f16)v;
                    }
                }
            } else {
                // V third: write transposed vtg[((b*H + h)*64 + d) * SEQ + s]
                int d = n - 2 * EMB;
                int hh = d >> 6, dd = d & 63;
#pragma unroll
                for (int mi = 0; mi < 2; mi++) {
#pragma unroll
                    for (int q = 0; q < 4; q++) {
                        int m0 = bm + wm + mi * 32 + 8 * q + 4 * l32;
                        int bb = m0 >> 10, s0 = m0 & (SEQ - 1);
                        f16x4 pack;
#pragma unroll
                        for (int r = 0; r < 4; r++) pack[r] = (f16)(acc[mi][ni][4 * q + r] + bv);
                        *(f16x4*)(vtg + ((size_t)((bb * NHEAD + hh) * HDIM + dd)) * SEQ + s0) = pack;
                    }
                }
            }
        }
    }
}

// ---------------- flash attention partials (split-KV, K/V double-buffered) --
// grid: (NCHUNK, S/64, BH). Chunk c covers j-tiles [4c, min(4c+3, qt)].
__global__ __launch_bounds__(256) void attn_part(const f16* __restrict__ qk,  // (B*S, 2E)
                                                 const f16* __restrict__ vtg, // (B,H,64,S)
                                                 f16* __restrict__ po,        // [NCHUNK][BH][SEQ][64]
                                                 float* __restrict__ pm,      // [NCHUNK][BH][SEQ]
                                                 float* __restrict__ pl,
                                                 const int* __restrict__ tt_p,
                                                 const int* __restrict__ rtc_p) {
    const int c = blockIdx.x;
    const int qt = blockIdx.y;
    if (c * 4 > qt) return;
    const int bh = blockIdx.z;
    const int b = bh / NHEAD, hh = bh % NHEAD;
    const int q0 = qt * 64;
    const int jt_beg = c * 4, jt_end = min(qt, c * 4 + 3);

    __shared__ f16 Qs[64 * 64];
    __shared__ f16 Ks[2][64 * 64];
    __shared__ f16 VT[2][64 * 64];
    __shared__ f16 Ps[4 * 16 * 64];

    const int tid = threadIdx.x, lane = tid & 63, wave = tid >> 6;
    const int l15 = lane & 15, l16 = lane >> 4;
    const int nt = *tt_p + 1;
    const int rtc = *rtc_p;
    const int RS = 2 * EMB;
    const f16* vth = vtg + (size_t)(b * NHEAD + hh) * HDIM * SEQ;
    const float SCALE2 = 0.125f * 1.44269504088896f;   // scale * log2(e)

    // ---- stage Q tile + first K/V tile (pre-swizzled source) ----
#pragma unroll
    for (int it = 0; it < 2; it++) {
        int R0 = wave * 16 + it * 8;
        int row = R0 + (lane >> 3), slot = lane & 7;
        int gs = (slot ^ (row & 7)) << 3;
        gload16(qk + (size_t)(b * SEQ + q0 + row) * RS + hh * HDIM + gs, Qs + R0 * 64);
        gload16(qk + (size_t)(b * SEQ + jt_beg * 64 + row) * RS + EMB + hh * HDIM + gs,
                Ks[0] + R0 * 64);
        gload16(vth + (size_t)row * SEQ + jt_beg * 64 + gs, VT[0] + R0 * 64);
    }
    __syncthreads();

    f16x8 qa[2];
#pragma unroll
    for (int ks = 0; ks < 2; ks++) {
        int row = wave * 16 + l15;
        int kslot = l16 + ks * 4;
        qa[ks] = *(const f16x8*)(Qs + row * 64 + ((kslot ^ (row & 7)) << 3));
    }

    float mrow[4], lsum[4];
    f32x4 o[4];
#pragma unroll
    for (int r = 0; r < 4; r++) { mrow[r] = -1e30f; lsum[r] = 0.f; }
#pragma unroll
    for (int nf = 0; nf < 4; nf++) o[nf] = (f32x4){0.f, 0.f, 0.f, 0.f};

    int iglob[4], idiv[4], imod[4], iok[4];
#pragma unroll
    for (int r = 0; r < 4; r++) {
        int i = q0 + wave * 16 + l16 * 4 + r;
        iglob[r] = i; idiv[r] = i / nt; imod[r] = i % nt;
        iok[r] = (i < rtc * nt);
    }

    for (int jt = jt_beg; jt <= jt_end; jt++) {
        const int j0 = jt * 64;
        const int cur = (jt - jt_beg) & 1;
        // ---- issue next tile's async loads (hidden under compute) ----
        if (jt < jt_end) {
            const int nxt = cur ^ 1;
            const int jn0 = (jt + 1) * 64;
#pragma unroll
            for (int it = 0; it < 2; it++) {
                int R0 = wave * 16 + it * 8;
                int row = R0 + (lane >> 3), slot = lane & 7;
                int gs = (slot ^ (row & 7)) << 3;
                gload16(qk + (size_t)(b * SEQ + jn0 + row) * RS + EMB + hh * HDIM + gs,
                        Ks[nxt] + R0 * 64);
                gload16(vth + (size_t)row * SEQ + jn0 + gs, VT[nxt] + R0 * 64);
            }
        }

        // ---- S = Q K^T ----
        f32x4 s[4];
#pragma unroll
        for (int nf = 0; nf < 4; nf++) {
            s[nf] = (f32x4){0.f, 0.f, 0.f, 0.f};
#pragma unroll
            for (int ks = 0; ks < 2; ks++) {
                int row = nf * 16 + l15;
                int kslot = l16 + ks * 4;
                f16x8 kb = *(const f16x8*)(Ks[cur] + row * 64 + ((kslot ^ (row & 7)) << 3));
                s[nf] = __builtin_amdgcn_mfma_f32_16x16x32_f16(qa[ks], kb, s[nf], 0, 0, 0);
            }
        }

        // ---- mask + online softmax (base-2) ----
        float p[4][4];
        float tmax[4] = {-1e30f, -1e30f, -1e30f, -1e30f};
#pragma unroll
        for (int nf = 0; nf < 4; nf++) {
            int j = j0 + nf * 16 + l15;
            int jd = j / nt, jm = j % nt;
#pragma unroll
            for (int r = 0; r < 4; r++) {
                bool same = (idiv[r] == jd) && (idiv[r] < rtc) && (imod[r] >= jm);
                bool sv   = (jm == 0) && (jd < rtc) && (iglob[r] > j) && iok[r];
                float val = (same || sv) ? s[nf][r] * SCALE2 : -1e30f;
                p[nf][r] = val;
                tmax[r] = fmaxf(tmax[r], val);
            }
        }
#pragma unroll
        for (int r = 0; r < 4; r++) {
            tmax[r] = fmaxf(tmax[r], __shfl_xor(tmax[r], 1));
            tmax[r] = fmaxf(tmax[r], __shfl_xor(tmax[r], 2));
            tmax[r] = fmaxf(tmax[r], __shfl_xor(tmax[r], 4));
            tmax[r] = fmaxf(tmax[r], __shfl_xor(tmax[r], 8));
        }
        float alpha[4], rsum[4], meff[4];
#pragma unroll
        for (int r = 0; r < 4; r++) {
            float mn = fmaxf(mrow[r], tmax[r]);
            alpha[r] = exp2f(mrow[r] - mn);
            mrow[r] = mn;
            meff[r] = (mn <= -1e29f) ? 0.f : mn;
            rsum[r] = 0.f;
        }
#pragma unroll
        for (int nf = 0; nf < 4; nf++)
#pragma unroll
            for (int r = 0; r < 4; r++) {
                float e = exp2f(p[nf][r] - meff[r]);
                p[nf][r] = e;
                rsum[r] += e;
            }
#pragma unroll
        for (int r = 0; r < 4; r++) {
            rsum[r] += __shfl_xor(rsum[r], 1);
            rsum[r] += __shfl_xor(rsum[r], 2);
            rsum[r] += __shfl_xor(rsum[r], 4);
            rsum[r] += __shfl_xor(rsum[r], 8);
            lsum[r] = lsum[r] * alpha[r] + rsum[r];
        }
#pragma unroll
        for (int nf = 0; nf < 4; nf++)
#pragma unroll
            for (int r = 0; r < 4; r++) o[nf][r] *= alpha[r];

        // ---- P -> per-wave LDS (wave-local, lgkm-ordered) ----
        f16* P = Ps + wave * 16 * 64;
#pragma unroll
        for (int nf = 0; nf < 4; nf++)
#pragma unroll
            for (int r = 0; r < 4; r++) {
                int prow = l16 * 4 + r;
                int pcol = nf * 16 + l15;
                P[prow * 64 + (((pcol >> 3) ^ (prow & 7)) << 3) + (pcol & 7)] = (f16)p[nf][r];
            }

        // ---- O += P @ V ----
#pragma unroll
        for (int ks = 0; ks < 2; ks++) {
            int kslot = l16 + ks * 4;
            int prow = l15;
            f16x8 pa = *(const f16x8*)(P + prow * 64 + ((kslot ^ (prow & 7)) << 3));
#pragma unroll
            for (int nf = 0; nf < 4; nf++) {
                int vrow = nf * 16 + l15;
                f16x8 vb = *(const f16x8*)(VT[cur] + vrow * 64 + ((kslot ^ (vrow & 7)) << 3));
                o[nf] = __builtin_amdgcn_mfma_f32_16x16x32_f16(pa, vb, o[nf], 0, 0, 0);
            }
        }
        // one barrier per step: drains next-tile loads AND protects buffer reuse
        __syncthreads();
    }

    // ---- write partials (unnormalized) ----
    const size_t base = (size_t)(c * BH + bh) * SEQ;
#pragma unroll
    for (int r = 0; r < 4; r++) {
        int i = q0 + wave * 16 + l16 * 4 + r;
#pragma unroll
        for (int nf = 0; nf < 4; nf++)
            po[(base + i) * 64 + nf * 16 + l15] = (f16)o[nf][r];
        if (l15 == 0) {
            pm[base + i] = mrow[r];
            pl[base + i] = lsum[r];
        }
    }
}

// ---------------- LN( h + attn_combine(po,pm,pl) ), wave-per-row ------------
__global__ __launch_bounds__(256) void add_ln_attn(const float* __restrict__ X,
                                                   const f16* __restrict__ po,
                                                   const float* __restrict__ pm,
                                                   const float* __restrict__ pl,
                                                   const float* __restrict__ w,
                                                   const float* __restrict__ bsh,
                                                   float* __restrict__ out32,
                                                   f16* __restrict__ out16) {
    const int row = blockIdx.x * 4 + (threadIdx.x >> 6);
    const int lane = threadIdx.x & 63;
    const int b = row >> 10, i = row & (SEQ - 1);
    const int nch = (i >> 6) / 4 + 1;   // chunks with 4c <= qt
    const float* xr = X + (size_t)row * EMB;
    float4 v[3];
    float s = 0.f;
#pragma unroll
    for (int t = 0; t < 3; t++) {
        int e = t * 256 + lane * 4;
        int hh = e >> 6, d = e & 63;
        size_t hbase = (size_t)(b * NHEAD + hh) * SEQ + i;
        float m = -1e30f;
        for (int c = 0; c < nch; c++) m = fmaxf(m, pm[hbase + (size_t)c * BH * SEQ]);
        float meff = (m <= -1e29f) ? 0.f : m;
        float lt = 0.f;
        float4 ov = {0.f, 0.f, 0.f, 0.f};
        for (int c = 0; c < nch; c++) {
            size_t idx = hbase + (size_t)c * BH * SEQ;
            float wgt = exp2f(pm[idx] - meff);
            lt += pl[idx] * wgt;
            f16x4 pv = *(const f16x4*)(po + idx * 64 + d);
            ov.x += (float)pv[0] * wgt; ov.y += (float)pv[1] * wgt;
            ov.z += (float)pv[2] * wgt; ov.w += (float)pv[3] * wgt;
        }
        float inv = (lt > 0.f) ? 1.0f / lt : 0.0f;
        float4 a = *(const float4*)(xr + e);
        a.x += ov.x * inv; a.y += ov.y * inv; a.z += ov.z * inv; a.w += ov.w * inv;
        v[t] = a;
        s += a.x + a.y + a.z + a.w;
    }
#pragma unroll
    for (int k = 1; k < 64; k <<= 1) s += __shfl_xor(s, k);
    float mu = s * (1.0f / EMB);
    float s2 = 0.f;
#pragma unroll
    for (int t = 0; t < 3; t++) {
        float dx = v[t].x - mu, dy = v[t].y - mu, dz = v[t].z - mu, dw = v[t].w - mu;
        s2 += dx * dx + dy * dy + dz * dz + dw * dw;
    }
#pragma unroll
    for (int k = 1; k < 64; k <<= 1) s2 += __shfl_xor(s2, k);
    float inv = rsqrtf(s2 * (1.0f / EMB) + 1e-5f);
#pragma unroll
    for (int t = 0; t < 3; t++) {
        int e = t * 256 + lane * 4;
        float4 wv = *(const float4*)(w + e);
        float4 bv = *(const float4*)(bsh + e);
        float4 o;
        o.x = (v[t].x - mu) * inv * wv.x + bv.x;
        o.y = (v[t].y - mu) * inv * wv.y + bv.y;
        o.z = (v[t].z - mu) * inv * wv.z + bv.z;
        o.w = (v[t].w - mu) * inv * wv.w + bv.w;
        *(float4*)(out32 + (size_t)row * EMB + e) = o;
        f16x4 hh;
        hh[0] = (f16)o.x; hh[1] = (f16)o.y; hh[2] = (f16)o.z; hh[3] = (f16)o.w;
        *(f16x4*)(out16 + (size_t)row * EMB + e) = hh;
    }
}

// ---------------- LN( h + bias + sum of 4 split-K partials ) ----------------
__global__ __launch_bounds__(256) void add_ln_split4(const float* __restrict__ X,
                                                     const float* __restrict__ part, // 4x ROWS*EMB
                                                     const float* __restrict__ bias,
                                                     const float* __restrict__ w,
                                                     const float* __restrict__ bsh,
                                                     float* __restrict__ out32,
                                                     f16* __restrict__ out16) {
    const int row = blockIdx.x * 4 + (threadIdx.x >> 6);
    const int lane = threadIdx.x & 63;
    const float* xr = X + (size_t)row * EMB;
    float4 v[3];
    float s = 0.f;
#pragma unroll
    for (int t = 0; t < 3; t++) {
        int e = t * 256 + lane * 4;
        float4 a = *(const float4*)(xr + e);
        float4 bb = *(const float4*)(bias + e);
        a.x += bb.x; a.y += bb.y; a.z += bb.z; a.w += bb.w;
#pragma unroll
        for (int z = 0; z < 4; z++) {
            float4 pz = *(const float4*)(part + (size_t)z * ROWS * EMB + (size_t)row * EMB + e);
            a.x += pz.x; a.y += pz.y; a.z += pz.z; a.w += pz.w;
        }
        v[t] = a;
        s += a.x + a.y + a.z + a.w;
    }
#pragma unroll
    for (int k = 1; k < 64; k <<= 1) s += __shfl_xor(s, k);
    float mu = s * (1.0f / EMB);
    float s2 = 0.f;
#pragma unroll
    for (int t = 0; t < 3; t++) {
        float dx = v[t].x - mu, dy = v[t].y - mu, dz = v[t].z - mu, dw = v[t].w - mu;
        s2 += dx * dx + dy * dy + dz * dz + dw * dw;
    }
#pragma unroll
    for (int k = 1; k < 64; k <<= 1) s2 += __shfl_xor(s2, k);
    float inv = rsqrtf(s2 * (1.0f / EMB) + 1e-5f);
#pragma unroll
    for (int t = 0; t < 3; t++) {
        int e = t * 256 + lane * 4;
        float4 wv = *(const float4*)(w + e);
        float4 bv = *(const float4*)(bsh + e);
        float4 o;
        o.x = (v[t].x - mu) * inv * wv.x + bv.x;
        o.y = (v[t].y - mu) * inv * wv.y + bv.y;
        o.z = (v[t].z - mu) * inv * wv.z + bv.z;
        o.w = (v[t].w - mu) * inv * wv.w + bv.w;
        *(float4*)(out32 + (size_t)row * EMB + e) = o;
        f16x4 hh;
        hh[0] = (f16)o.x; hh[1] = (f16)o.y; hh[2] = (f16)o.z; hh[3] = (f16)o.w;
        *(f16x4*)(out16 + (size_t)row * EMB + e) = hh;
    }
}

// ---------------- plain final LN --------------------------------------------
__global__ __launch_bounds__(256) void ln_final(const float* __restrict__ X,
                                                const float* __restrict__ w,
                                                const float* __restrict__ bsh,
                                                float* __restrict__ out32) {
    const int row = blockIdx.x * 4 + (threadIdx.x >> 6);
    const int lane = threadIdx.x & 63;
    const float* xr = X + (size_t)row * EMB;
    float4 v[3];
    float s = 0.f;
#pragma unroll
    for (int t = 0; t < 3; t++) {
        int e = t * 256 + lane * 4;
        v[t] = *(const float4*)(xr + e);
        s += v[t].x + v[t].y + v[t].z + v[t].w;
    }
#pragma unroll
    for (int k = 1; k < 64; k <<= 1) s += __shfl_xor(s, k);
    float mu = s * (1.0f / EMB);
    float s2 = 0.f;
#pragma unroll
    for (int t = 0; t < 3; t++) {
        float dx = v[t].x - mu, dy = v[t].y - mu, dz = v[t].z - mu, dw = v[t].w - mu;
        s2 += dx * dx + dy * dy + dz * dz + dw * dw;
    }
#pragma unroll
    for (int k = 1; k < 64; k <<= 1) s2 += __shfl_xor(s2, k);
    float inv = rsqrtf(s2 * (1.0f / EMB) + 1e-5f);
#pragma unroll
    for (int t = 0; t < 3; t++) {
        int e = t * 256 + lane * 4;
        float4 wv = *(const float4*)(w + e);
        float4 bv = *(const float4*)(bsh + e);
        float4 o;
        o.x = (v[t].x - mu) * inv * wv.x + bv.x;
        o.y = (v[t].y - mu) * inv * wv.y + bv.y;
        o.z = (v[t].z - mu) * inv * wv.z + bv.z;
        o.w = (v[t].w - mu) * inv * wv.w + bv.w;
        *(float4*)(out32 + (size_t)row * EMB + e) = o;
    }
}

extern "C" void kernel_launch(void* const* d_in, const int* in_sizes, int n_in,
                              void* d_out, int out_size, void* d_ws, size_t ws_size,
                              hipStream_t stream) {
    const float* x      = (const float*)d_in[0];
    const float* tpe    = (const float*)d_in[2];
    const float* Wqkv   = (const float*)d_in[3];
    const float* bqkv   = (const float*)d_in[4];
    const float* W1     = (const float*)d_in[5];
    const float* b1     = (const float*)d_in[6];
    const float* W2     = (const float*)d_in[7];
    const float* b2     = (const float*)d_in[8];
    const float* ln1_w  = (const float*)d_in[9];
    const float* ln1_b  = (const float*)d_in[10];
    const float* ln2_w  = (const float*)d_in[11];
    const float* ln2_b  = (const float*)d_in[12];
    const float* lnf_w  = (const float*)d_in[13];
    const float* lnf_b  = (const float*)d_in[14];
    const int*   tt     = (const int*)d_in[15];
    const int*   rtc    = (const int*)d_in[16];
    float* out = (float*)d_out;

    // workspace layout (bytes)
    char* wsp = (char*)d_ws;
    float* h32  = (float*)wsp;                       //  6,291,456
    f16*   h16  = (f16*)(wsp + 6291456);             //  3,145,728
    f16*   act  = (f16*)(wsp + 9437184);             //  8,388,608 (qk 2048x1536 / ff1 2048x2048)
    f16*   vtg  = (f16*)(wsp + 17825792);            //  3,145,728 (B,H,64,S)
    float* part = (float*)(wsp + 20971520);          // 25,165,824 (4x ROWS*EMB f32)
    f16*   wbuf = (f16*)(wsp + 46137344);            // 39,321,600 (ALL layers f16 weights)
    f16*   po   = (f16*)(wsp + 85458944);            // 12,582,912
    float* pm   = (float*)(wsp + 98041856);          //    393,216
    float* pl   = (float*)(wsp + 98435072);          //    393,216  -> total 98,828,288

    const int EQ = 3 * EMB * EMB;      // per-layer Wqkv elems
    const int E1 = FFDIM * EMB;        // per-layer W1 elems
    const int E2 = EMB * FFDIM;        // per-layer W2 elems
    f16* wqAll = wbuf;
    f16* w1All = wbuf + (size_t)NLAYER * EQ;
    f16* w2All = w1All + (size_t)NLAYER * E1;

    // cast ALL layers' weights in one launch (sources are layer-contiguous)
    cast3<<<4096, 256, 0, stream>>>(Wqkv, NLAYER * EQ / 4, W1, NLAYER * E1 / 4,
                                    W2, NLAYER * E2 / 4, wqAll, w1All, w2All);

    embed_kernel<<<(BATCH * SEQ * EMB + 255) / 256, 256, 0, stream>>>(x, tpe, h32, h16, tt, rtc);

    for (int l = 0; l < NLAYER; l++) {
        const f16* wq16 = wqAll + (size_t)l * EQ;
        const f16* w116 = w1All + (size_t)l * E1;
        const f16* w216 = w2All + (size_t)l * E2;
        const float* bq  = bqkv + (size_t)l * 3 * EMB;
        const float* bb1 = b1 + (size_t)l * FFDIM;
        const float* bb2 = b2 + (size_t)l * EMB;

        // qkv: Q,K -> act (stride 1536), V -> vtg transposed
        gemm_f16<0, 2><<<dim3(3 * EMB / 128, ROWS / 128), 256, 0, stream>>>(
            h16, wq16, bq, nullptr, act, vtg, ROWS, 3 * EMB, EMB);

        // attention partials
        attn_part<<<dim3(NCHUNK, SEQ / 64, BH), 256, 0, stream>>>(act, vtg, po, pm, pl, tt, rtc);

        // h = LN(h + combine(po)) — combine fused into LN
        add_ln_attn<<<ROWS / 4, 256, 0, stream>>>(h32, po, pm, pl,
                                                  ln1_w + l * EMB, ln1_b + l * EMB, h32, h16);

        // ff1 = gelu(h @ W1^T + b1) -> act (f16, 2048x2048)
        gemm_f16<1, 1><<<dim3(FFDIM / 128, ROWS / 128), 256, 0, stream>>>(
            h16, w116, bb1, nullptr, act, nullptr, ROWS, FFDIM, EMB);

        // ff2 partials: raw acc -> part[z], split-K x4 (K chunk = 512)
        gemm_f16<0, 3><<<dim3(EMB / 128, ROWS / 128, 4), 256, 0, stream>>>(
            act, w216, nullptr, part, nullptr, nullptr, ROWS, EMB, FFDIM);

        // h = LN(h + b2 + sum(part)) — reduction fused into LN
        add_ln_split4<<<ROWS / 4, 256, 0, stream>>>(h32, part, bb2,
                                                    ln2_w + l * EMB, ln2_b + l * EMB, h32, h16);
    }

    ln_final<<<ROWS / 4, 256, 0, stream>>>(h32, lnf_w, lnf_b, out);
}

// Round 7
// 450.718 us; speedup vs baseline: 19.1669x; 1.0548x over previous
//
#include <hip/hip_runtime.h>
#include <math.h>

#define SEQ 1024
#define EMB 768
#define NHEAD 12
#define HDIM 64
#define NLAYER 4
#define FFDIM 2048
#define BATCH 2
#define ROWS (BATCH * SEQ)   // 2048
#define BH (BATCH * NHEAD)   // 24
#define NCHUNK 4             // KV chunks of 4 tiles (256 keys)

using f16 = _Float16;
using f16x4 = __attribute__((ext_vector_type(4))) _Float16;
using f16x8 = __attribute__((ext_vector_type(8))) _Float16;
using f32x4 = __attribute__((ext_vector_type(4))) float;
using f32x16 = __attribute__((ext_vector_type(16))) float;
typedef unsigned long long u64;

__device__ inline void gload16(const void* g, void* l) {
    __builtin_amdgcn_global_load_lds((const __attribute__((address_space(1))) unsigned*)g,
                                     (__attribute__((address_space(3))) unsigned*)l, 16, 0, 0);
}

// ---------------- embed: h = x + sinusoidal_pe + thought_pe ----------------
__global__ void embed_kernel(const float* __restrict__ x,
                             const float* __restrict__ tpe,
                             float* __restrict__ h32,
                             f16* __restrict__ h16,
                             const int* __restrict__ tt_p,
                             const int* __restrict__ rtc_p) {
    int idx = blockIdx.x * blockDim.x + threadIdx.x;  // over B*S*E
    if (idx >= BATCH * SEQ * EMB) return;
    int e = idx % EMB;
    int s = (idx / EMB) % SEQ;
    int nt = *tt_p + 1;
    int rtc = *rtc_p;
    float val;
    if (s < rtc * nt) {
        int p = s / nt;
        int t = s % nt;
        int i2 = e & ~1;
        float div = __expf((float)i2 * -0.0119926314f);  // -ln(10000)/768
        float ang = (float)p * div;
        float pe = (e & 1) ? __cosf(ang) : __sinf(ang);
        val = x[idx] + pe + tpe[t * EMB + e];
    } else {
        val = 0.0f;
    }
    h32[idx] = val;
    h16[idx] = (f16)val;
}

// ---------------- block-causal mask bit-table: mtab[i][jt] ------------------
__global__ void build_mask(u64* __restrict__ mtab,
                           const int* __restrict__ tt_p,
                           const int* __restrict__ rtc_p) {
    int idx = blockIdx.x * blockDim.x + threadIdx.x;  // SEQ*16
    if (idx >= SEQ * 16) return;
    int i = idx >> 4, jt = idx & 15;
    int nt = *tt_p + 1, rtc = *rtc_p;
    int id = i / nt, im = i % nt;
    int iok = (i < rtc * nt);
    u64 m = 0;
    for (int k = 0; k < 64; k++) {
        int j = jt * 64 + k;
        int jd = j / nt, jm = j % nt;
        bool same = (id == jd) && (id < rtc) && (im >= jm);
        bool sv   = (jm == 0) && (jd < rtc) && (i > j) && iok;
        if (same || sv) m |= (1ull << k);
    }
    mtab[idx] = m;
}

// ---------------- all-layer weight cast (3 contiguous regions, 1 launch) ----
__global__ void cast3(const float* __restrict__ a, int na,
                      const float* __restrict__ b, int nb,
                      const float* __restrict__ c, int nc,
                      f16* __restrict__ oa, f16* __restrict__ ob, f16* __restrict__ oc) {
    int total = na + nb + nc;   // float4 units
    for (int i = blockIdx.x * blockDim.x + threadIdx.x; i < total;
         i += gridDim.x * blockDim.x) {
        const float* src;
        f16* dst;
        int off;
        if (i < na)            { src = a; dst = oa; off = i; }
        else if (i < na + nb)  { src = b; dst = ob; off = i - na; }
        else                   { src = c; dst = oc; off = i - na - nb; }
        float4 v = ((const float4*)src)[off];
        f16x4 o;
        o[0] = (f16)v.x; o[1] = (f16)v.y; o[2] = (f16)v.z; o[3] = (f16)v.w;
        ((f16x4*)dst)[off] = o;
    }
}

// ---------------- MFMA GEMM (32x32x16): C = A @ W^T (+ bias) -----------------
// OUT: 1 = f16 out (+bias, opt GELU); 2 = qkv split (Q,K f16 stride 2E +bias,
//      V transposed +bias -> vtg[b,h,d,s]); 3 = f16 raw-acc partials to
//      Ch + z*ROWS*N (split-K; bias added downstream)
template<int ACT, int OUT>
__global__ __launch_bounds__(256) void gemm_f16(const f16* __restrict__ A,
                                                const f16* __restrict__ W,
                                                const float* __restrict__ bias,
                                                f16* __restrict__ Ch,
                                                f16* __restrict__ vtg,
                                                int M, int N, int K) {
    __shared__ f16 As[128 * 64];
    __shared__ f16 Ws[128 * 64];
    const int tid = threadIdx.x, lane = tid & 63, wave = tid >> 6;
    // XCD-aware block swizzle (bijective when nwg % 8 == 0)
    const int gx = gridDim.x;
    const int nwg = gx * gridDim.y;
    int orig = blockIdx.y * gx + blockIdx.x;
    int nid = (nwg & 7) ? orig : ((orig & 7) * (nwg >> 3) + (orig >> 3));
    const int bm = (nid / gx) * 128, bn = (nid % gx) * 128;
    const int l31 = lane & 31, l32 = lane >> 5;
    const int wm = (wave >> 1) * 64, wn = (wave & 1) * 64;
    const int srow = lane >> 3, sslot = lane & 7;
    const int klen = K / gridDim.z;
    const int kbeg = blockIdx.z * klen, kend = kbeg + klen;

    f32x16 acc[2][2];
#pragma unroll
    for (int mi = 0; mi < 2; mi++)
#pragma unroll
        for (int ni = 0; ni < 2; ni++)
#pragma unroll
            for (int e = 0; e < 16; e++) acc[mi][ni][e] = 0.f;

    for (int k0 = kbeg; k0 < kend; k0 += 64) {
#pragma unroll
        for (int i = 0; i < 4; i++) {
            int R0 = wave * 32 + i * 8;
            int row = R0 + srow;
            int gs = (sslot ^ (row & 7)) << 3;
            gload16(A + (size_t)(bm + row) * K + k0 + gs, As + R0 * 64);
            gload16(W + (size_t)(bn + row) * K + k0 + gs, Ws + R0 * 64);
        }
        __syncthreads();
#pragma unroll
        for (int ks = 0; ks < 4; ks++) {
            int kslot = ks * 2 + l32;   // 8 f16 k-elems per slot
            f16x8 a[2], b[2];
#pragma unroll
            for (int mi = 0; mi < 2; mi++) {
                int row = wm + mi * 32 + l31;
                a[mi] = *(const f16x8*)(As + row * 64 + ((kslot ^ (row & 7)) << 3));
            }
#pragma unroll
            for (int ni = 0; ni < 2; ni++) {
                int row = wn + ni * 32 + l31;
                b[ni] = *(const f16x8*)(Ws + row * 64 + ((kslot ^ (row & 7)) << 3));
            }
#pragma unroll
            for (int mi = 0; mi < 2; mi++)
#pragma unroll
                for (int ni = 0; ni < 2; ni++)
                    acc[mi][ni] = __builtin_amdgcn_mfma_f32_32x32x16_f16(a[mi], b[ni], acc[mi][ni], 0, 0, 0);
        }
        __syncthreads();
    }

    // epilogue: C row = (reg&3) + 8*(reg>>2) + 4*(lane>>5), col = lane&31
#pragma unroll
    for (int ni = 0; ni < 2; ni++) {
        int nbase = bn + wn + ni * 32;
        int n = nbase + l31;
        if (OUT == 3) {
            f16* dst = Ch + (size_t)blockIdx.z * ROWS * N;
#pragma unroll
            for (int mi = 0; mi < 2; mi++)
#pragma unroll
                for (int reg = 0; reg < 16; reg++) {
                    int m = bm + wm + mi * 32 + (reg & 3) + 8 * (reg >> 2) + 4 * l32;
                    dst[(size_t)m * N + n] = (f16)acc[mi][ni][reg];
                }
        } else {
            float bv = bias[n];
            if (OUT != 2 || nbase < 2 * EMB) {
                int cstride = (OUT == 2) ? 2 * EMB : N;
#pragma unroll
                for (int mi = 0; mi < 2; mi++) {
#pragma unroll
                    for (int reg = 0; reg < 16; reg++) {
                        int m = bm + wm + mi * 32 + (reg & 3) + 8 * (reg >> 2) + 4 * l32;
                        float v = acc[mi][ni][reg] + bv;
                        if (ACT) v = 0.5f * v * (1.0f + erff(v * 0.70710678118654752f));
                        Ch[(size_t)m * cstride + n] = (f16)v;
                    }
                }
            } else {
                // V third: write transposed vtg[((b*H + h)*64 + d) * SEQ + s]
                int d = n - 2 * EMB;
                int hh = d >> 6, dd = d & 63;
#pragma unroll
                for (int mi = 0; mi < 2; mi++) {
#pragma unroll
                    for (int q = 0; q < 4; q++) {
                        int m0 = bm + wm + mi * 32 + 8 * q + 4 * l32;
                        int bb = m0 >> 10, s0 = m0 & (SEQ - 1);
                        f16x4 pack;
#pragma unroll
                        for (int r = 0; r < 4; r++) pack[r] = (f16)(acc[mi][ni][4 * q + r] + bv);
                        *(f16x4*)(vtg + ((size_t)((bb * NHEAD + hh) * HDIM + dd)) * SEQ + s0) = pack;
                    }
                }
            }
        }
    }
}

// ---------------- flash attention partials (split-KV, dbuf, mask table) -----
// grid: (NCHUNK, S/64, BH). Chunk c covers j-tiles [4c, min(4c+3, qt)].
__global__ __launch_bounds__(256) void attn_part(const f16* __restrict__ qk,  // (B*S, 2E)
                                                 const f16* __restrict__ vtg, // (B,H,64,S)
                                                 const u64* __restrict__ mtab,// [SEQ][16]
                                                 f16* __restrict__ po,        // [NCHUNK][BH][SEQ][64]
                                                 float* __restrict__ pm,      // [NCHUNK][BH][SEQ]
                                                 float* __restrict__ pl) {
    const int c = blockIdx.x;
    const int qt = blockIdx.y;
    if (c * 4 > qt) return;
    const int bh = blockIdx.z;
    const int b = bh / NHEAD, hh = bh % NHEAD;
    const int q0 = qt * 64;
    const int jt_beg = c * 4, jt_end = min(qt, c * 4 + 3);

    __shared__ f16 Qs[64 * 64];
    __shared__ f16 Ks[2][64 * 64];
    __shared__ f16 VT[2][64 * 64];
    __shared__ f16 Ps[4 * 16 * 64];

    const int tid = threadIdx.x, lane = tid & 63, wave = tid >> 6;
    const int l15 = lane & 15, l16 = lane >> 4;
    const int RS = 2 * EMB;
    const f16* vth = vtg + (size_t)(b * NHEAD + hh) * HDIM * SEQ;
    const float SCALE2 = 0.125f * 1.44269504088896f;   // scale * log2(e)

    // ---- stage Q tile + first K/V tile (pre-swizzled source) ----
#pragma unroll
    for (int it = 0; it < 2; it++) {
        int R0 = wave * 16 + it * 8;
        int row = R0 + (lane >> 3), slot = lane & 7;
        int gs = (slot ^ (row & 7)) << 3;
        gload16(qk + (size_t)(b * SEQ + q0 + row) * RS + hh * HDIM + gs, Qs + R0 * 64);
        gload16(qk + (size_t)(b * SEQ + jt_beg * 64 + row) * RS + EMB + hh * HDIM + gs,
                Ks[0] + R0 * 64);
        gload16(vth + (size_t)row * SEQ + jt_beg * 64 + gs, VT[0] + R0 * 64);
    }
    __syncthreads();

    f16x8 qa[2];
#pragma unroll
    for (int ks = 0; ks < 2; ks++) {
        int row = wave * 16 + l15;
        int kslot = l16 + ks * 4;
        qa[ks] = *(const f16x8*)(Qs + row * 64 + ((kslot ^ (row & 7)) << 3));
    }

    float mrow[4], lsum[4];
    f32x4 o[4];
    int iglob[4];
#pragma unroll
    for (int r = 0; r < 4; r++) {
        mrow[r] = -1e30f; lsum[r] = 0.f;
        iglob[r] = q0 + wave * 16 + l16 * 4 + r;
    }
#pragma unroll
    for (int nf = 0; nf < 4; nf++) o[nf] = (f32x4){0.f, 0.f, 0.f, 0.f};

    for (int jt = jt_beg; jt <= jt_end; jt++) {
        const int cur = (jt - jt_beg) & 1;
        // ---- issue next tile's async loads (hidden under compute) ----
        if (jt < jt_end) {
            const int nxt = cur ^ 1;
            const int jn0 = (jt + 1) * 64;
#pragma unroll
            for (int it = 0; it < 2; it++) {
                int R0 = wave * 16 + it * 8;
                int row = R0 + (lane >> 3), slot = lane & 7;
                int gs = (slot ^ (row & 7)) << 3;
                gload16(qk + (size_t)(b * SEQ + jn0 + row) * RS + EMB + hh * HDIM + gs,
                        Ks[nxt] + R0 * 64);
                gload16(vth + (size_t)row * SEQ + jn0 + gs, VT[nxt] + R0 * 64);
            }
        }

        // ---- fetch mask words for this j-tile (broadcast per 16-lane group) --
        unsigned mlo[4], mhi[4];
#pragma unroll
        for (int r = 0; r < 4; r++) {
            u64 mk = mtab[iglob[r] * 16 + jt];
            mlo[r] = (unsigned)mk;
            mhi[r] = (unsigned)(mk >> 32);
        }

        // ---- S = Q K^T ----
        f32x4 s[4];
        __builtin_amdgcn_s_setprio(1);
#pragma unroll
        for (int nf = 0; nf < 4; nf++) {
            s[nf] = (f32x4){0.f, 0.f, 0.f, 0.f};
#pragma unroll
            for (int ks = 0; ks < 2; ks++) {
                int row = nf * 16 + l15;
                int kslot = l16 + ks * 4;
                f16x8 kb = *(const f16x8*)(Ks[cur] + row * 64 + ((kslot ^ (row & 7)) << 3));
                s[nf] = __builtin_amdgcn_mfma_f32_16x16x32_f16(qa[ks], kb, s[nf], 0, 0, 0);
            }
        }
        __builtin_amdgcn_s_setprio(0);

        // ---- mask (bit-table) + online softmax (base-2) ----
        float p[4][4];
        float tmax[4] = {-1e30f, -1e30f, -1e30f, -1e30f};
#pragma unroll
        for (int nf = 0; nf < 4; nf++) {
            int sh = (nf & 1) * 16 + l15;
#pragma unroll
            for (int r = 0; r < 4; r++) {
                unsigned w = (nf & 2) ? mhi[r] : mlo[r];
                bool allowed = (w >> sh) & 1;
                float val = allowed ? s[nf][r] * SCALE2 : -1e30f;
                p[nf][r] = val;
                tmax[r] = fmaxf(tmax[r], val);
            }
        }
#pragma unroll
        for (int r = 0; r < 4; r++) {
            tmax[r] = fmaxf(tmax[r], __shfl_xor(tmax[r], 1));
            tmax[r] = fmaxf(tmax[r], __shfl_xor(tmax[r], 2));
            tmax[r] = fmaxf(tmax[r], __shfl_xor(tmax[r], 4));
            tmax[r] = fmaxf(tmax[r], __shfl_xor(tmax[r], 8));
        }
        float alpha[4], rsum[4], meff[4];
#pragma unroll
        for (int r = 0; r < 4; r++) {
            float mn = fmaxf(mrow[r], tmax[r]);
            alpha[r] = exp2f(mrow[r] - mn);
            mrow[r] = mn;
            meff[r] = (mn <= -1e29f) ? 0.f : mn;
            rsum[r] = 0.f;
        }
#pragma unroll
        for (int nf = 0; nf < 4; nf++)
#pragma unroll
            for (int r = 0; r < 4; r++) {
                float e = exp2f(p[nf][r] - meff[r]);
                p[nf][r] = e;
                rsum[r] += e;
            }
#pragma unroll
        for (int r = 0; r < 4; r++) {
            rsum[r] += __shfl_xor(rsum[r], 1);
            rsum[r] += __shfl_xor(rsum[r], 2);
            rsum[r] += __shfl_xor(rsum[r], 4);
            rsum[r] += __shfl_xor(rsum[r], 8);
            lsum[r] = lsum[r] * alpha[r] + rsum[r];
        }
#pragma unroll
        for (int nf = 0; nf < 4; nf++)
#pragma unroll
            for (int r = 0; r < 4; r++) o[nf][r] *= alpha[r];

        // ---- P -> per-wave LDS (wave-local, lgkm-ordered) ----
        f16* P = Ps + wave * 16 * 64;
#pragma unroll
        for (int nf = 0; nf < 4; nf++)
#pragma unroll
            for (int r = 0; r < 4; r++) {
                int prow = l16 * 4 + r;
                int pcol = nf * 16 + l15;
                P[prow * 64 + (((pcol >> 3) ^ (prow & 7)) << 3) + (pcol & 7)] = (f16)p[nf][r];
            }

        // ---- O += P @ V ----
        __builtin_amdgcn_s_setprio(1);
#pragma unroll
        for (int ks = 0; ks < 2; ks++) {
            int kslot = l16 + ks * 4;
            int prow = l15;
            f16x8 pa = *(const f16x8*)(P + prow * 64 + ((kslot ^ (prow & 7)) << 3));
#pragma unroll
            for (int nf = 0; nf < 4; nf++) {
                int vrow = nf * 16 + l15;
                f16x8 vb = *(const f16x8*)(VT[cur] + vrow * 64 + ((kslot ^ (vrow & 7)) << 3));
                o[nf] = __builtin_amdgcn_mfma_f32_16x16x32_f16(pa, vb, o[nf], 0, 0, 0);
            }
        }
        __builtin_amdgcn_s_setprio(0);
        // one barrier per step: drains next-tile loads AND protects buffer reuse
        __syncthreads();
    }

    // ---- write partials (unnormalized) ----
    const size_t base = (size_t)(c * BH + bh) * SEQ;
#pragma unroll
    for (int r = 0; r < 4; r++) {
        int i = q0 + wave * 16 + l16 * 4 + r;
#pragma unroll
        for (int nf = 0; nf < 4; nf++)
            po[(base + i) * 64 + nf * 16 + l15] = (f16)o[nf][r];
        if (l15 == 0) {
            pm[base + i] = mrow[r];
            pl[base + i] = lsum[r];
        }
    }
}

// ---------------- LN( h + attn_combine(po,pm,pl) ), wave-per-row ------------
__global__ __launch_bounds__(256) void add_ln_attn(const float* __restrict__ X,
                                                   const f16* __restrict__ po,
                                                   const float* __restrict__ pm,
                                                   const float* __restrict__ pl,
                                                   const float* __restrict__ w,
                                                   const float* __restrict__ bsh,
                                                   float* __restrict__ out32,
                                                   f16* __restrict__ out16) {
    const int row = blockIdx.x * 4 + (threadIdx.x >> 6);
    const int lane = threadIdx.x & 63;
    const int b = row >> 10, i = row & (SEQ - 1);
    const int nch = (i >> 6) / 4 + 1;   // chunks with 4c <= qt
    const float* xr = X + (size_t)row * EMB;
    float4 v[3];
    float s = 0.f;
#pragma unroll
    for (int t = 0; t < 3; t++) {
        int e = t * 256 + lane * 4;
        int hh = e >> 6, d = e & 63;
        size_t hbase = (size_t)(b * NHEAD + hh) * SEQ + i;
        float m = -1e30f;
        for (int c = 0; c < nch; c++) m = fmaxf(m, pm[hbase + (size_t)c * BH * SEQ]);
        float meff = (m <= -1e29f) ? 0.f : m;
        float lt = 0.f;
        float4 ov = {0.f, 0.f, 0.f, 0.f};
        for (int c = 0; c < nch; c++) {
            size_t idx = hbase + (size_t)c * BH * SEQ;
            float wgt = exp2f(pm[idx] - meff);
            lt += pl[idx] * wgt;
            f16x4 pv = *(const f16x4*)(po + idx * 64 + d);
            ov.x += (float)pv[0] * wgt; ov.y += (float)pv[1] * wgt;
            ov.z += (float)pv[2] * wgt; ov.w += (float)pv[3] * wgt;
        }
        float inv = (lt > 0.f) ? 1.0f / lt : 0.0f;
        float4 a = *(const float4*)(xr + e);
        a.x += ov.x * inv; a.y += ov.y * inv; a.z += ov.z * inv; a.w += ov.w * inv;
        v[t] = a;
        s += a.x + a.y + a.z + a.w;
    }
#pragma unroll
    for (int k = 1; k < 64; k <<= 1) s += __shfl_xor(s, k);
    float mu = s * (1.0f / EMB);
    float s2 = 0.f;
#pragma unroll
    for (int t = 0; t < 3; t++) {
        float dx = v[t].x - mu, dy = v[t].y - mu, dz = v[t].z - mu, dw = v[t].w - mu;
        s2 += dx * dx + dy * dy + dz * dz + dw * dw;
    }
#pragma unroll
    for (int k = 1; k < 64; k <<= 1) s2 += __shfl_xor(s2, k);
    float inv = rsqrtf(s2 * (1.0f / EMB) + 1e-5f);
#pragma unroll
    for (int t = 0; t < 3; t++) {
        int e = t * 256 + lane * 4;
        float4 wv = *(const float4*)(w + e);
        float4 bv = *(const float4*)(bsh + e);
        float4 o;
        o.x = (v[t].x - mu) * inv * wv.x + bv.x;
        o.y = (v[t].y - mu) * inv * wv.y + bv.y;
        o.z = (v[t].z - mu) * inv * wv.z + bv.z;
        o.w = (v[t].w - mu) * inv * wv.w + bv.w;
        *(float4*)(out32 + (size_t)row * EMB + e) = o;
        f16x4 hh;
        hh[0] = (f16)o.x; hh[1] = (f16)o.y; hh[2] = (f16)o.z; hh[3] = (f16)o.w;
        *(f16x4*)(out16 + (size_t)row * EMB + e) = hh;
    }
}

// ---------------- LN( h + bias + sum of 4 f16 split-K partials ) ------------
__global__ __launch_bounds__(256) void add_ln_split4(const float* __restrict__ X,
                                                     const f16* __restrict__ part, // 4x ROWS*EMB f16
                                                     const float* __restrict__ bias,
                                                     const float* __restrict__ w,
                                                     const float* __restrict__ bsh,
                                                     float* __restrict__ out32,
                                                     f16* __restrict__ out16) {
    const int row = blockIdx.x * 4 + (threadIdx.x >> 6);
    const int lane = threadIdx.x & 63;
    const float* xr = X + (size_t)row * EMB;
    float4 v[3];
    float s = 0.f;
#pragma unroll
    for (int t = 0; t < 3; t++) {
        int e = t * 256 + lane * 4;
        float4 a = *(const float4*)(xr + e);
        float4 bb = *(const float4*)(bias + e);
        a.x += bb.x; a.y += bb.y; a.z += bb.z; a.w += bb.w;
#pragma unroll
        for (int z = 0; z < 4; z++) {
            f16x4 pz = *(const f16x4*)(part + (size_t)z * ROWS * EMB + (size_t)row * EMB + e);
            a.x += (float)pz[0]; a.y += (float)pz[1];
            a.z += (float)pz[2]; a.w += (float)pz[3];
        }
        v[t] = a;
        s += a.x + a.y + a.z + a.w;
    }
#pragma unroll
    for (int k = 1; k < 64; k <<= 1) s += __shfl_xor(s, k);
    float mu = s * (1.0f / EMB);
    float s2 = 0.f;
#pragma unroll
    for (int t = 0; t < 3; t++) {
        float dx = v[t].x - mu, dy = v[t].y - mu, dz = v[t].z - mu, dw = v[t].w - mu;
        s2 += dx * dx + dy * dy + dz * dz + dw * dw;
    }
#pragma unroll
    for (int k = 1; k < 64; k <<= 1) s2 += __shfl_xor(s2, k);
    float inv = rsqrtf(s2 * (1.0f / EMB) + 1e-5f);
#pragma unroll
    for (int t = 0; t < 3; t++) {
        int e = t * 256 + lane * 4;
        float4 wv = *(const float4*)(w + e);
        float4 bv = *(const float4*)(bsh + e);
        float4 o;
        o.x = (v[t].x - mu) * inv * wv.x + bv.x;
        o.y = (v[t].y - mu) * inv * wv.y + bv.y;
        o.z = (v[t].z - mu) * inv * wv.z + bv.z;
        o.w = (v[t].w - mu) * inv * wv.w + bv.w;
        *(float4*)(out32 + (size_t)row * EMB + e) = o;
        f16x4 hh;
        hh[0] = (f16)o.x; hh[1] = (f16)o.y; hh[2] = (f16)o.z; hh[3] = (f16)o.w;
        *(f16x4*)(out16 + (size_t)row * EMB + e) = hh;
    }
}

// ---------------- plain final LN --------------------------------------------
__global__ __launch_bounds__(256) void ln_final(const float* __restrict__ X,
                                                const float* __restrict__ w,
                                                const float* __restrict__ bsh,
                                                float* __restrict__ out32) {
    const int row = blockIdx.x * 4 + (threadIdx.x >> 6);
    const int lane = threadIdx.x & 63;
    const float* xr = X + (size_t)row * EMB;
    float4 v[3];
    float s = 0.f;
#pragma unroll
    for (int t = 0; t < 3; t++) {
        int e = t * 256 + lane * 4;
        v[t] = *(const float4*)(xr + e);
        s += v[t].x + v[t].y + v[t].z + v[t].w;
    }
#pragma unroll
    for (int k = 1; k < 64; k <<= 1) s += __shfl_xor(s, k);
    float mu = s * (1.0f / EMB);
    float s2 = 0.f;
#pragma unroll
    for (int t = 0; t < 3; t++) {
        float dx = v[t].x - mu, dy = v[t].y - mu, dz = v[t].z - mu, dw = v[t].w - mu;
        s2 += dx * dx + dy * dy + dz * dz + dw * dw;
    }
#pragma unroll
    for (int k = 1; k < 64; k <<= 1) s2 += __shfl_xor(s2, k);
    float inv = rsqrtf(s2 * (1.0f / EMB) + 1e-5f);
#pragma unroll
    for (int t = 0; t < 3; t++) {
        int e = t * 256 + lane * 4;
        float4 wv = *(const float4*)(w + e);
        float4 bv = *(const float4*)(bsh + e);
        float4 o;
        o.x = (v[t].x - mu) * inv * wv.x + bv.x;
        o.y = (v[t].y - mu) * inv * wv.y + bv.y;
        o.z = (v[t].z - mu) * inv * wv.z + bv.z;
        o.w = (v[t].w - mu) * inv * wv.w + bv.w;
        *(float4*)(out32 + (size_t)row * EMB + e) = o;
    }
}

extern "C" void kernel_launch(void* const* d_in, const int* in_sizes, int n_in,
                              void* d_out, int out_size, void* d_ws, size_t ws_size,
                              hipStream_t stream) {
    const float* x      = (const float*)d_in[0];
    const float* tpe    = (const float*)d_in[2];
    const float* Wqkv   = (const float*)d_in[3];
    const float* bqkv   = (const float*)d_in[4];
    const float* W1     = (const float*)d_in[5];
    const float* b1     = (const float*)d_in[6];
    const float* W2     = (const float*)d_in[7];
    const float* b2     = (const float*)d_in[8];
    const float* ln1_w  = (const float*)d_in[9];
    const float* ln1_b  = (const float*)d_in[10];
    const float* ln2_w  = (const float*)d_in[11];
    const float* ln2_b  = (const float*)d_in[12];
    const float* lnf_w  = (const float*)d_in[13];
    const float* lnf_b  = (const float*)d_in[14];
    const int*   tt     = (const int*)d_in[15];
    const int*   rtc    = (const int*)d_in[16];
    float* out = (float*)d_out;

    // workspace layout (bytes)
    char* wsp = (char*)d_ws;
    float* h32  = (float*)wsp;                       //  6,291,456
    f16*   h16  = (f16*)(wsp + 6291456);             //  3,145,728
    f16*   act  = (f16*)(wsp + 9437184);             //  8,388,608 (qk 2048x1536 / ff1 2048x2048)
    f16*   vtg  = (f16*)(wsp + 17825792);            //  3,145,728 (B,H,64,S)
    f16*   part = (f16*)(wsp + 20971520);            // 12,582,912 (4x ROWS*EMB f16)
    f16*   wbuf = (f16*)(wsp + 33554432);            // 39,321,600 (ALL layers f16 weights)
    f16*   po   = (f16*)(wsp + 72876032);            // 12,582,912
    float* pm   = (float*)(wsp + 85458944);          //    393,216
    float* pl   = (float*)(wsp + 85852160);          //    393,216
    u64*   mtab = (u64*)(wsp + 86245376);            //    131,072  -> total 86,376,448

    const int EQ = 3 * EMB * EMB;      // per-layer Wqkv elems
    const int E1 = FFDIM * EMB;        // per-layer W1 elems
    const int E2 = EMB * FFDIM;        // per-layer W2 elems
    f16* wqAll = wbuf;
    f16* w1All = wbuf + (size_t)NLAYER * EQ;
    f16* w2All = w1All + (size_t)NLAYER * E1;

    // one-time: weight cast (all layers), embed, mask bit-table
    cast3<<<4096, 256, 0, stream>>>(Wqkv, NLAYER * EQ / 4, W1, NLAYER * E1 / 4,
                                    W2, NLAYER * E2 / 4, wqAll, w1All, w2All);
    embed_kernel<<<(BATCH * SEQ * EMB + 255) / 256, 256, 0, stream>>>(x, tpe, h32, h16, tt, rtc);
    build_mask<<<SEQ * 16 / 256, 256, 0, stream>>>(mtab, tt, rtc);

    for (int l = 0; l < NLAYER; l++) {
        const f16* wq16 = wqAll + (size_t)l * EQ;
        const f16* w116 = w1All + (size_t)l * E1;
        const f16* w216 = w2All + (size_t)l * E2;
        const float* bq  = bqkv + (size_t)l * 3 * EMB;
        const float* bb1 = b1 + (size_t)l * FFDIM;
        const float* bb2 = b2 + (size_t)l * EMB;

        // qkv: Q,K -> act (stride 1536), V -> vtg transposed
        gemm_f16<0, 2><<<dim3(3 * EMB / 128, ROWS / 128), 256, 0, stream>>>(
            h16, wq16, bq, act, vtg, ROWS, 3 * EMB, EMB);

        // attention partials
        attn_part<<<dim3(NCHUNK, SEQ / 64, BH), 256, 0, stream>>>(act, vtg, mtab, po, pm, pl);

        // h = LN(h + combine(po)) — combine fused into LN
        add_ln_attn<<<ROWS / 4, 256, 0, stream>>>(h32, po, pm, pl,
                                                  ln1_w + l * EMB, ln1_b + l * EMB, h32, h16);

        // ff1 = gelu(h @ W1^T + b1) -> act (f16, 2048x2048)
        gemm_f16<1, 1><<<dim3(FFDIM / 128, ROWS / 128), 256, 0, stream>>>(
            h16, w116, bb1, act, nullptr, ROWS, FFDIM, EMB);

        // ff2 partials: raw acc (f16) -> part[z], split-K x4 (K chunk = 512)
        gemm_f16<0, 3><<<dim3(EMB / 128, ROWS / 128, 4), 256, 0, stream>>>(
            act, w216, nullptr, part, nullptr, ROWS, EMB, FFDIM);

        // h = LN(h + b2 + sum(part)) — reduction fused into LN
        add_ln_split4<<<ROWS / 4, 256, 0, stream>>>(h32, part, bb2,
                                                    ln2_w + l * EMB, ln2_b + l * EMB, h32, h16);
    }

    ln_final<<<ROWS / 4, 256, 0, stream>>>(h32, lnf_w, lnf_b, out);
}